// Round 2
// baseline (684.569 us; speedup 1.0000x reference)
//
#include <hip/hip_runtime.h>

typedef __bf16 bf16x8 __attribute__((ext_vector_type(8)));
typedef float f32x4 __attribute__((ext_vector_type(4)));
typedef unsigned short u16;
typedef unsigned int u32;

#define QSCALE 0.08838834764831845f  // 1/sqrt(128)

static __device__ __forceinline__ float bf2f(u16 u) {
  union { float f; u32 i; } x; x.i = ((u32)u) << 16; return x.f;
}
static __device__ __forceinline__ u16 f2bf(float f) {
  union { float f; u32 i; } x; x.f = f;
  u32 r = x.i + 0x7fffu + ((x.i >> 16) & 1u);
  return (u16)(r >> 16);
}
// async global->LDS, 16B per lane; lds dest must be wave-uniform base (+lane*16 by HW)
static __device__ __forceinline__ void gload16(const void* gp, void* lp) {
  __builtin_amdgcn_global_load_lds(
      (const __attribute__((address_space(1))) u32*)gp,
      (__attribute__((address_space(3))) u32*)lp, 16, 0, 0);
}

// ---------------- convert activations f32 -> bf16 ----------------
__global__ __launch_bounds__(256) void k_conv_acts(
    const float* __restrict__ hs, const float* __restrict__ ehs, const float* __restrict__ iph,
    u16* __restrict__ hsb, u16* __restrict__ ehsb, u16* __restrict__ ipb)
{
  int i = blockIdx.x * 256 + threadIdx.x;
  const float* s; u16* d; int j;
  if (i < 786432)        { s = hs;  d = hsb;  j = i; }
  else if (i < 1179648)  { s = ehs; d = ehsb; j = i - 786432; }
  else                   { s = iph; d = ipb;  j = i - 1179648; }
  float4 v = ((const float4*)s)[j];
  uint2 o;
  o.x = (u32)f2bf(v.x) | ((u32)f2bf(v.y) << 16);
  o.y = (u32)f2bf(v.z) | ((u32)f2bf(v.w) << 16);
  ((uint2*)d)[j] = o;
}

// ---------------- weight transpose+convert: src (K,3072) f32 -> dst (3072,K) bf16 ----------------
// lane = n mapping: global reads coalesced (lanes span n); LDS is dword-granular,
// fully XOR-swizzled (pitch 32 dw == 0 mod 32, col' = c ^ (n&31)) -> both phases
// conflict-free (2 lanes/bank). Store phase repacks 4 swizzled dwords -> uint4.
struct WT { const float* src; u16* dst; int K; };
struct WTPack { WT w[10]; };

__global__ __launch_bounds__(256) void k_transp_w(WTPack p)
{
  WT d = p.w[blockIdx.z];
  int K = d.K;
  int k0 = blockIdx.y * 64;
  if (k0 >= K) return;
  int n0 = blockIdx.x * 64;
  __shared__ u32 T[64 * 32];   // row n: 32 dwords (64 bf16), swizzled
  int t = threadIdx.x;
  int n = t & 63, kg = t >> 6;                  // kg = wave id: k-quarter
  const float* s = d.src + (size_t)(k0 + kg * 16) * 3072 + n0 + n;
  u32* row = T + n * 32;
  int sw = n & 31;
  #pragma unroll
  for (int j = 0; j < 8; j++) {
    float a = s[(size_t)(2 * j) * 3072];
    float b = s[(size_t)(2 * j + 1) * 3072];
    row[(kg * 8 + j) ^ sw] = (u32)f2bf(a) | ((u32)f2bf(b) << 16);
  }
  __syncthreads();
  #pragma unroll
  for (int i = 0; i < 2; i++) {
    int idx = t + i * 256;
    int nn = idx >> 3, ch = idx & 7;
    const u32* r2 = T + nn * 32;
    int s2 = nn & 31;
    uint4 o;
    o.x = r2[(ch * 4 + 0) ^ s2];
    o.y = r2[(ch * 4 + 1) ^ s2];
    o.z = r2[(ch * 4 + 2) ^ s2];
    o.w = r2[(ch * 4 + 3) ^ s2];
    *(uint4*)(d.dst + (size_t)(n0 + nn) * K + k0 + ch * 8) = o;
  }
}

// ---------------- 8-phase 256x256 GEMM, 8 waves, counted-vmcnt pipeline ----------------
// LDS per operand: [buf2][kh2][row256][ch4 * 8bf16], chunk slot ch holds logical k-chunk ch^(row&3).
// Per K-tile (BK=64): 4 phases x 16 MFMA; each phase issues ONE half-tile (2x gload16) of prefetch.
// kh0 of tile t is read in p0/p1; p2/p3 overwrite it with tile t+2 (safe after p1 barrier).
// vmcnt(8) at p1 covers kh1(t) [read p2/p3]; vmcnt(8) at p3 covers kh0(t+1) [read next p0/p1].
struct G8Job { const u16* A; const u16* W; const float* bias; void* C; int M; int K; int blk0; int out_f32; };
struct G8Pack { G8Job j[8]; int njobs; };

__global__ __launch_bounds__(512, 2) void k_gemm8(G8Pack p)
{
  extern __shared__ __align__(16) u16 smem[];
  u16* As = smem;            // 32768 u16 = 64KB
  u16* Bs = smem + 32768;    // 64KB

  int bid = blockIdx.x;
  bid = (bid & 7) * 30 + (bid >> 3);      // XCD swizzle; grid is exactly 240 = 8*30
  int ji = 0;
  while (ji + 1 < p.njobs && bid >= p.j[ji + 1].blk0) ji++;
  G8Job J = p.j[ji];
  int local = bid - J.blk0;
  int m0 = (local / 12) * 256;
  int n0 = (local % 12) * 256;
  int K = J.K, NT = K >> 6;

  int tid = threadIdx.x, w = tid >> 6, lane = tid & 63, l15 = lane & 15, quad = lane >> 4;
  int wm = (w >> 2) * 128, wn = (w & 3) * 64;
  int dw = w * 512;                        // wave-uniform LDS slot base (u16 units)
  int cread = (quad ^ (l15 & 3)) * 8;      // frag chunk offset (u16)

  int rr = tid >> 2;                       // staging row within 128-row round
  int c4 = ((tid & 3) ^ (rr & 3)) * 8;     // pre-swizzled global chunk (u16)
  const u16* pa0 = J.A + (size_t)(m0 + rr) * K + c4;
  const u16* pa1 = pa0 + (size_t)128 * K;
  const u16* pb0 = J.W + (size_t)(n0 + rr) * K + c4;
  const u16* pb1 = pb0 + (size_t)128 * K;

  f32x4 acc[8][4] = {};
  bf16x8 af[4], bfr[4];

#define STAGE_A(b, kh, tt) do { int _ko = (tt) * 64 + (kh) * 32; int _d = ((b) * 2 + (kh)) * 8192 + dw; \
    gload16(pa0 + _ko, As + _d); gload16(pa1 + _ko, As + _d + 4096); } while (0)
#define STAGE_B(b, kh, tt) do { int _ko = (tt) * 64 + (kh) * 32; int _d = ((b) * 2 + (kh)) * 8192 + dw; \
    gload16(pb0 + _ko, Bs + _d); gload16(pb1 + _ko, Bs + _d + 4096); } while (0)

  // prologue: tile0 fully, tile1 kh0. 12 loads issued; wait leaves kh0(1) in flight.
  STAGE_A(0, 0, 0); STAGE_B(0, 0, 0); STAGE_A(0, 1, 0); STAGE_B(0, 1, 0);
  STAGE_A(1, 0, 1); STAGE_B(1, 0, 1);
  __asm__ volatile("s_waitcnt vmcnt(4)" ::: "memory");
  __builtin_amdgcn_s_barrier();

#define PHASE(ks, mtb, READB, STAGES, WAITS) do { \
    int _ab = (cur * 2 + (ks)) * 8192; \
    _Pragma("unroll") for (int i = 0; i < 4; i++) \
      af[i] = *(const bf16x8*)(As + _ab + (wm + ((mtb) + i) * 16 + l15) * 32 + cread); \
    if (READB) { _Pragma("unroll") for (int i = 0; i < 4; i++) \
      bfr[i] = *(const bf16x8*)(Bs + _ab + (wn + i * 16 + l15) * 32 + cread); } \
    STAGES; WAITS; \
    __builtin_amdgcn_s_barrier(); \
    __asm__ volatile("s_waitcnt lgkmcnt(0)" ::: "memory"); \
    __builtin_amdgcn_sched_barrier(0); \
    __builtin_amdgcn_s_setprio(1); \
    _Pragma("unroll") for (int mt = 0; mt < 4; mt++) \
      _Pragma("unroll") for (int nt = 0; nt < 4; nt++) \
        acc[(mtb) + mt][nt] = __builtin_amdgcn_mfma_f32_16x16x32_bf16(af[mt], bfr[nt], acc[(mtb) + mt][nt], 0, 0, 0); \
    __builtin_amdgcn_s_setprio(0); \
    __builtin_amdgcn_sched_barrier(0); \
    __builtin_amdgcn_s_barrier(); \
  } while (0)

  int cur = 0;
  for (int t = 0; t < NT; t++) {
    int o = cur ^ 1;
    int t1 = (t + 1 < NT) ? t + 1 : NT - 1;   // clamped prefetch (tail writes unread regions)
    int t2 = (t + 2 < NT) ? t + 2 : NT - 1;
    PHASE(0, 0, 1, STAGE_A(o, 1, t1), (void)0);
    PHASE(0, 4, 0, STAGE_B(o, 1, t1), __asm__ volatile("s_waitcnt vmcnt(8)" ::: "memory"));
    PHASE(1, 0, 1, STAGE_A(cur, 0, t2), (void)0);
    PHASE(1, 4, 0, STAGE_B(cur, 0, t2), __asm__ volatile("s_waitcnt vmcnt(8)" ::: "memory"));
    cur = o;
  }
  __asm__ volatile("s_waitcnt vmcnt(0)" ::: "memory");  // drain before LDS dealloc

  #pragma unroll
  for (int mt = 0; mt < 8; mt++) {
    int row = m0 + wm + mt * 16 + quad * 4;
    #pragma unroll
    for (int nt = 0; nt < 4; nt++) {
      int col = n0 + wn + nt * 16 + l15;
      float bv = J.bias[col];
      #pragma unroll
      for (int r = 0; r < 4; r++) {
        if (row + r < J.M) {
          float v = acc[mt][nt][r] + bv;
          if (J.out_f32) ((float*)J.C)[(size_t)(row + r) * 3072 + col] = v;
          else           ((u16*)J.C)[(size_t)(row + r) * 3072 + col] = f2bf(v);
        }
      }
    }
  }
#undef PHASE
#undef STAGE_A
#undef STAGE_B
}

// ---------------- batched GEMM (2-phase, kept for output projections) ----------------
struct GJob { const u16* A; const u16* W; const float* bias; void* C; int M; int K; int blk0; int out_f32; };
struct GPack { GJob j[8]; int njobs; };

template<int MT>
__global__ __launch_bounds__(256) void k_gemm(GPack p)
{
  __shared__ u16 As[MT * 64];
  __shared__ u16 Bs[128 * 64];
  int bid = blockIdx.x;
  int ji = 0;
  while (ji + 1 < p.njobs && bid >= p.j[ji+1].blk0) ji++;
  GJob J = p.j[ji];
  int local = bid - J.blk0;
  int m0 = (local / 24) * MT;
  int n0 = (local % 24) * 128;

  int tid = threadIdx.x, w = tid >> 6, lane = tid & 63, l15 = lane & 15, quad = lane >> 4;
  constexpr int MF = MT / 32;
  int wm = (w >> 1) * (MT / 2), wn = (w & 1) * 64;
  f32x4 acc[MF][4] = {};

  constexpr int GA = MT * 8 / 256;
  const u16* Ag[GA]; const u16* Bg[4];
  #pragma unroll
  for (int i = 0; i < GA; i++) {
    int s = i * 256 + tid;
    int row = s >> 3, kc = (s & 7) ^ (row & 7);
    Ag[i] = J.A + (size_t)(m0 + row) * J.K + kc * 8;
  }
  #pragma unroll
  for (int i = 0; i < 4; i++) {
    int s = i * 256 + tid;
    int row = s >> 3, kc = (s & 7) ^ (row & 7);
    Bg[i] = J.W + (size_t)(n0 + row) * J.K + kc * 8;
  }

  for (int k0 = 0; k0 < J.K; k0 += 64) {
    #pragma unroll
    for (int i = 0; i < GA; i++)
      gload16(Ag[i] + k0, As + (size_t)(i * 256 + w * 64) * 8);
    #pragma unroll
    for (int i = 0; i < 4; i++)
      gload16(Bg[i] + k0, Bs + (size_t)(i * 256 + w * 64) * 8);
    __syncthreads();
    int x7 = l15 & 7;
    #pragma unroll
    for (int ks = 0; ks < 2; ks++) {
      bf16x8 af[MF], bfr[4];
      #pragma unroll
      for (int t = 0; t < MF; t++)
        af[t] = *(const bf16x8*)(As + (wm + t * 16 + l15) * 64 + (((ks * 4 + quad) ^ x7) * 8));
      #pragma unroll
      for (int t = 0; t < 4; t++)
        bfr[t] = *(const bf16x8*)(Bs + (wn + t * 16 + l15) * 64 + (((ks * 4 + quad) ^ x7) * 8));
      #pragma unroll
      for (int mt = 0; mt < MF; mt++)
        #pragma unroll
        for (int nt = 0; nt < 4; nt++)
          acc[mt][nt] = __builtin_amdgcn_mfma_f32_16x16x32_bf16(af[mt], bfr[nt], acc[mt][nt], 0, 0, 0);
    }
    __syncthreads();
  }

  #pragma unroll
  for (int mt = 0; mt < MF; mt++) {
    int row = m0 + wm + mt * 16 + quad * 4;
    #pragma unroll
    for (int nt = 0; nt < 4; nt++) {
      int col = n0 + wn + nt * 16 + l15;
      float bv = J.bias[col];
      #pragma unroll
      for (int r = 0; r < 4; r++) {
        if (row + r < J.M) {
          float v = acc[mt][nt][r] + bv;
          if (J.out_f32) ((float*)J.C)[(size_t)(row + r) * 3072 + col] = v;
          else           ((u16*)J.C)[(size_t)(row + r) * 3072 + col] = f2bf(v);
        }
      }
    }
  }
}

// ---------------- pack Q/K: RMS + RoPE + scale, head-major ----------------
__global__ __launch_bounds__(256) void k_pack_qk(
    const u16* __restrict__ q, const u16* __restrict__ k,
    const u16* __restrict__ eq, const u16* __restrict__ ek,
    const u16* __restrict__ ipk,
    const float* __restrict__ cosr, const float* __restrict__ sinr,
    const float* __restrict__ nq, const float* __restrict__ nk,
    const float* __restrict__ naq, const float* __restrict__ nak,
    const float* __restrict__ nipq, const float* __restrict__ nipk,
    u16* __restrict__ Qf, u16* __restrict__ Kf, u16* __restrict__ Qip, u16* __restrict__ Kip)
{
  int u = blockIdx.x * 4 + (threadIdx.x >> 6);
  int lane = threadIdx.x & 63;
  int d0 = lane * 2;
  if (u < 36864) {
    int t = u / 24, h = u % 24;
    bool txt = t < 512;
    const u16* qrow = txt ? eq + (size_t)t * 3072 : q + (size_t)(t - 512) * 3072;
    const u16* krow = txt ? ek + (size_t)t * 3072 : k + (size_t)(t - 512) * 3072;
    u32 qv = ((const u32*)(qrow + h * 128))[lane];
    u32 kv = ((const u32*)(krow + h * 128))[lane];
    float q0 = bf2f((u16)qv), q1 = bf2f((u16)(qv >> 16));
    float k0 = bf2f((u16)kv), k1 = bf2f((u16)(kv >> 16));
    float sq = q0 * q0 + q1 * q1, sk = k0 * k0 + k1 * k1;
    #pragma unroll
    for (int off = 32; off > 0; off >>= 1) {
      sq += __shfl_xor(sq, off, 64);
      sk += __shfl_xor(sk, off, 64);
    }
    float rq = rsqrtf(sq * (1.0f / 128.0f) + 1e-6f);
    float rk = rsqrtf(sk * (1.0f / 128.0f) + 1e-6f);
    const float* wq = txt ? naq : nq;
    const float* wk = txt ? nak : nk;
    float2 c = ((const float2*)(cosr + (size_t)t * 128))[lane];
    float2 s = ((const float2*)(sinr + (size_t)t * 128))[lane];
    float xq0 = q0 * rq * wq[d0] * QSCALE, xq1 = q1 * rq * wq[d0 + 1] * QSCALE;
    float xk0 = k0 * rk * wk[d0],          xk1 = k1 * rk * wk[d0 + 1];
    u32 oq = (u32)f2bf(xq0 * c.x - xq1 * s.x) | ((u32)f2bf(xq1 * c.y + xq0 * s.y) << 16);
    u32 ok = (u32)f2bf(xk0 * c.x - xk1 * s.x) | ((u32)f2bf(xk1 * c.y + xk0 * s.y) << 16);
    ((u32*)(Qf + ((size_t)h * 1536 + t) * 128))[lane] = oq;
    ((u32*)(Kf + ((size_t)h * 1536 + t) * 128))[lane] = ok;
    if (!txt) {
      float y0 = q0 * rq * nipq[d0] * QSCALE, y1 = q1 * rq * nipq[d0 + 1] * QSCALE;
      u32 oy = (u32)f2bf(y0) | ((u32)f2bf(y1) << 16);
      ((u32*)(Qip + ((size_t)h * 1024 + (t - 512)) * 128))[lane] = oy;
    }
  } else {
    int u2 = u - 36864;
    if (u2 < 384) {
      int h = u2 >> 4, t = u2 & 15;
      u32 v = ((const u32*)(ipk + (size_t)t * 3072 + h * 128))[lane];
      float x0 = bf2f((u16)v), x1 = bf2f((u16)(v >> 16));
      float ss = x0 * x0 + x1 * x1;
      #pragma unroll
      for (int off = 32; off > 0; off >>= 1) ss += __shfl_xor(ss, off, 64);
      float rr = rsqrtf(ss * (1.0f / 128.0f) + 1e-6f);
      u32 o = (u32)f2bf(x0 * rr * nipk[d0]) | ((u32)f2bf(x1 * rr * nipk[d0 + 1]) << 16);
      ((u32*)(Kip + ((size_t)h * 64 + t) * 128))[lane] = o;   // Kip padded to 64 keys
    }
  }
}

// ---------------- pack V transposed: Vt (24,128,1536), Vipt (24,128,64) zero-padded ----------------
__global__ __launch_bounds__(256) void k_pack_v(
    const u16* __restrict__ v, const u16* __restrict__ ev, const u16* __restrict__ ipv,
    u16* __restrict__ Vt, u16* __restrict__ Vipt)
{
  __shared__ u16 T[64 * 72];
  int h = blockIdx.x, y = blockIdx.y, tid = threadIdx.x;
  if (y < 48) {
    int tb = (y % 24) * 64, db = (y / 24) * 64;
    #pragma unroll
    for (int i = 0; i < 2; i++) {
      int idx = tid + i * 256;
      int r = idx >> 3, ch = idx & 7;
      int t = tb + r;
      const u16* src = (t < 512) ? ev + (size_t)t * 3072 : v + (size_t)(t - 512) * 3072;
      uint4 val = *(const uint4*)(src + h * 128 + db + ch * 8);
      u16 tmp[8];
      *(uint4*)tmp = val;
      #pragma unroll
      for (int j = 0; j < 8; j++) T[(ch * 8 + j) * 72 + r] = tmp[j];
    }
    __syncthreads();
    #pragma unroll
    for (int i = 0; i < 2; i++) {
      int idx = tid + i * 256;
      int r = idx >> 3, ch = idx & 7;
      uint4 val = *(const uint4*)(T + r * 72 + ch * 8);
      *(uint4*)(Vt + ((size_t)h * 128 + db + r) * 1536 + tb + ch * 8) = val;
    }
  } else {
    if (tid < 128) {
      #pragma unroll
      for (int t = 0; t < 64; t++) {
        u16 val = 0;
        if (t < 16) val = ipv[(size_t)t * 3072 + h * 128 + tid];
        Vipt[((size_t)h * 128 + tid) * 64 + t] = val;  // zero pad keys 16..63
      }
    }
  }
}

// ---------------- flash attention, transposed-score formulation ----------------
__global__ __launch_bounds__(256) void k_attn(
    const u16* __restrict__ Q, const u16* __restrict__ K, const u16* __restrict__ V,
    const float* __restrict__ addend, void* __restrict__ out,
    int Sq, int Skv, int Skv_valid, int mode)
{
  __shared__ u16 Ks[64 * 128];   // [key][d-chunk swizzled]: chunk' = ch ^ (key&15)
  __shared__ u16 Vs[128 * 64];   // [d][key-chunk swizzled]: chunk' = ch ^ (d&7)
  __shared__ u16 Ps[4 * 16 * 68];
  int tid = threadIdx.x, h = blockIdx.y;
  int w = tid >> 6, lane = tid & 63, l15 = lane & 15, quad = lane >> 4;
  int mb = blockIdx.x * 64 + w * 16;

  bf16x8 aq[4];
  {
    const u16* qp = Q + ((size_t)h * Sq + mb + l15) * 128 + quad * 8;
    #pragma unroll
    for (int c = 0; c < 4; c++) aq[c] = *(const bf16x8*)(qp + c * 32);
  }

  const u16* Kg[4]; const u16* Vg[4];
  #pragma unroll
  for (int i = 0; i < 4; i++) {
    int s = tid + i * 256;
    int key = s >> 4, kc = (s & 15) ^ (key & 15);
    Kg[i] = K + ((size_t)h * Skv + key) * 128 + kc * 8;
    int d = s >> 3, vc = (s & 7) ^ (d & 7);
    Vg[i] = V + ((size_t)h * 128 + d) * Skv + vc * 8;
  }

  f32x4 o[8] = {};
  float m_col = -3.0e38f, l_col = 0.0f;
  u16* myPs = Ps + w * (16 * 68);

  for (int kb = 0; kb < Skv; kb += 64) {
    #pragma unroll
    for (int i = 0; i < 4; i++) {
      gload16(Kg[i] + (size_t)kb * 128, Ks + (i * 256 + w * 64) * 8);
      gload16(Vg[i] + kb,               Vs + (i * 256 + w * 64) * 8);
    }
    __syncthreads();

    f32x4 sc[4];
    #pragma unroll
    for (int mt = 0; mt < 4; mt++) {
      f32x4 a = {0.f, 0.f, 0.f, 0.f};
      int key = mt * 16 + l15;
      #pragma unroll
      for (int c = 0; c < 4; c++) {
        bf16x8 kf = *(const bf16x8*)(Ks + key * 128 + (((c * 4 + quad) ^ l15) * 8));
        a = __builtin_amdgcn_mfma_f32_16x16x32_bf16(kf, aq[c], a, 0, 0, 0);
      }
      sc[mt] = a;
    }
    if (Skv_valid != Skv) {
      #pragma unroll
      for (int mt = 0; mt < 4; mt++)
        #pragma unroll
        for (int r = 0; r < 4; r++)
          if (kb + mt * 16 + quad * 4 + r >= Skv_valid) sc[mt][r] = -1e30f;
    }

    float mx = sc[0][0];
    #pragma unroll
    for (int mt = 0; mt < 4; mt++)
      #pragma unroll
      for (int r = 0; r < 4; r++) mx = fmaxf(mx, sc[mt][r]);
    mx = fmaxf(mx, __shfl_xor(mx, 16, 64));
    mx = fmaxf(mx, __shfl_xor(mx, 32, 64));
    float mn = fmaxf(m_col, mx);
    float alpha = __expf(m_col - mn);
    m_col = mn;

    float sum = 0.f;
    #pragma unroll
    for (int mt = 0; mt < 4; mt++) {
      u16 pk[4];
      #pragma unroll
      for (int r = 0; r < 4; r++) {
        float pp = __expf(sc[mt][r] - mn);
        sum += pp;
        pk[r] = f2bf(pp);
      }
      uint2 pv;
      pv.x = (u32)pk[0] | ((u32)pk[1] << 16);
      pv.y = (u32)pk[2] | ((u32)pk[3] << 16);
      *(uint2*)(myPs + l15 * 68 + mt * 16 + quad * 4) = pv;
    }
    sum += __shfl_xor(sum, 16, 64);
    sum += __shfl_xor(sum, 32, 64);
    l_col = l_col * alpha + sum;

    float ar[4];
    #pragma unroll
    for (int r = 0; r < 4; r++) ar[r] = __shfl(alpha, quad * 4 + r, 64);
    #pragma unroll
    for (int nt = 0; nt < 8; nt++) {
      o[nt][0] *= ar[0]; o[nt][1] *= ar[1]; o[nt][2] *= ar[2]; o[nt][3] *= ar[3];
    }

    __asm__ volatile("s_waitcnt lgkmcnt(0)" ::: "memory");
    #pragma unroll
    for (int kc = 0; kc < 2; kc++) {
      bf16x8 pa = *(const bf16x8*)(myPs + l15 * 68 + kc * 32 + quad * 8);
      #pragma unroll
      for (int nt = 0; nt < 8; nt++) {
        int d = nt * 16 + l15;
        bf16x8 vf = *(const bf16x8*)(Vs + d * 64 + (((kc * 4 + quad) ^ (d & 7)) * 8));
        o[nt] = __builtin_amdgcn_mfma_f32_16x16x32_bf16(pa, vf, o[nt], 0, 0, 0);
      }
    }
    __syncthreads();
  }

  float linv = 1.0f / l_col;
  float lr[4];
  #pragma unroll
  for (int r = 0; r < 4; r++) lr[r] = __shfl(linv, quad * 4 + r, 64);
  #pragma unroll
  for (int r = 0; r < 4; r++) {
    int t = mb + quad * 4 + r;
    size_t base = (size_t)t * 3072 + h * 128 + l15;
    if (mode == 0) {
      float* O = (float*)out;
      #pragma unroll
      for (int nt = 0; nt < 8; nt++) O[base + nt * 16] = o[nt][r] * lr[r];
    } else {
      u16* O = (u16*)out;
      #pragma unroll
      for (int nt = 0; nt < 8; nt++) {
        float vv = o[nt][r] * lr[r];
        if (t >= 512) vv += addend[(size_t)(t - 512) * 3072 + h * 128 + nt * 16 + l15];
        O[base + nt * 16] = f2bf(vv);
      }
    }
  }
}

extern "C" void kernel_launch(void* const* d_in, const int* in_sizes, int n_in,
                              void* d_out, int out_size, void* d_ws, size_t ws_size,
                              hipStream_t stream) {
  const float* hs   = (const float*)d_in[0];
  const float* ehs  = (const float*)d_in[1];
  const float* iph  = (const float*)d_in[2];
  const float* cosr = (const float*)d_in[3];
  const float* sinr = (const float*)d_in[4];
  const float* Wq   = (const float*)d_in[5];  const float* bq   = (const float*)d_in[6];
  const float* Wk   = (const float*)d_in[7];  const float* bk   = (const float*)d_in[8];
  const float* Wv   = (const float*)d_in[9];  const float* bv   = (const float*)d_in[10];
  const float* nq   = (const float*)d_in[11]; const float* nk   = (const float*)d_in[12];
  const float* Waq  = (const float*)d_in[13]; const float* baq  = (const float*)d_in[14];
  const float* Wak  = (const float*)d_in[15]; const float* bak  = (const float*)d_in[16];
  const float* Wav  = (const float*)d_in[17]; const float* bav  = (const float*)d_in[18];
  const float* naq  = (const float*)d_in[19]; const float* nak  = (const float*)d_in[20];
  const float* Wo   = (const float*)d_in[21]; const float* bo   = (const float*)d_in[22];
  const float* Wad  = (const float*)d_in[23]; const float* bad  = (const float*)d_in[24];
  const float* Wkip = (const float*)d_in[25]; const float* bkip = (const float*)d_in[26];
  const float* Wvip = (const float*)d_in[27]; const float* bvip = (const float*)d_in[28];
  const float* nipq = (const float*)d_in[29]; const float* nipk = (const float*)d_in[30];
  (void)in_sizes; (void)n_in; (void)out_size; (void)ws_size;

  char* ws = (char*)d_ws;
  size_t off = 0;
  auto alloc = [&](size_t bytes) { size_t o = off; off += (bytes + 255) & ~(size_t)255; return o; };

  u16* hsb  = (u16*)(ws + alloc((size_t)1024 * 3072 * 2));
  u16* ehsb = (u16*)(ws + alloc((size_t)512 * 3072 * 2));
  u16* ipb  = (u16*)(ws + alloc((size_t)16 * 2048 * 2));
  u16* WT_[10];
  for (int i = 0; i < 10; i++) WT_[i] = (u16*)(ws + alloc((size_t)3072 * (i < 8 ? 3072 : 2048) * 2));
  u16* qb   = (u16*)(ws + alloc((size_t)1024 * 3072 * 2));
  u16* kb_  = (u16*)(ws + alloc((size_t)1024 * 3072 * 2));
  u16* vb   = (u16*)(ws + alloc((size_t)1024 * 3072 * 2));
  u16* eqb  = (u16*)(ws + alloc((size_t)512 * 3072 * 2));
  u16* ekb  = (u16*)(ws + alloc((size_t)512 * 3072 * 2));
  u16* evb  = (u16*)(ws + alloc((size_t)512 * 3072 * 2));
  u16* ipkb = (u16*)(ws + alloc((size_t)16 * 3072 * 2));
  u16* ipvb = (u16*)(ws + alloc((size_t)16 * 3072 * 2));
  u16* Qf   = (u16*)(ws + alloc((size_t)24 * 1536 * 128 * 2));
  u16* Kff  = (u16*)(ws + alloc((size_t)24 * 1536 * 128 * 2));
  u16* Vt   = (u16*)(ws + alloc((size_t)24 * 128 * 1536 * 2));
  u16* Qip  = (u16*)(ws + alloc((size_t)24 * 1024 * 128 * 2));
  u16* Kip  = (u16*)(ws + alloc((size_t)24 * 64 * 128 * 2));
  u16* Vipt = (u16*)(ws + alloc((size_t)24 * 128 * 64 * 2));
  float* ip_out = (float*)(ws + alloc((size_t)1024 * 3072 * 4));
  u16* attnb = (u16*)(ws + alloc((size_t)1536 * 3072 * 2));

  // allow 128KB dynamic LDS for the 8-phase GEMM (once)
  static bool attr_done = false;
  if (!attr_done) {
    hipFuncSetAttribute((const void*)k_gemm8, hipFuncAttributeMaxDynamicSharedMemorySize, 131072);
    attr_done = true;
  }

  k_conv_acts<<<4640, 256, 0, stream>>>(hs, ehs, iph, hsb, ehsb, ipb);

  WTPack p;
  const float* wsrc[10] = {Wq, Wk, Wv, Waq, Wak, Wav, Wo, Wad, Wkip, Wvip};
  for (int i = 0; i < 10; i++) { p.w[i].src = wsrc[i]; p.w[i].dst = WT_[i]; p.w[i].K = (i < 8 ? 3072 : 2048); }
  k_transp_w<<<dim3(48, 48, 10), 256, 0, stream>>>(p);

  // all 8 projection GEMMs in one 8-phase 256x256 dispatch (grid 240 = 8*30)
  {
    G8Pack pp;
    const u16* As_[8]  = {hsb, hsb, hsb, ehsb, ehsb, ehsb, ipb, ipb};
    const u16* Ws_[8]  = {WT_[0], WT_[1], WT_[2], WT_[3], WT_[4], WT_[5], WT_[8], WT_[9]};
    const float* bs_[8] = {bq, bk, bv, baq, bak, bav, bkip, bvip};
    u16* Cs_[8]        = {qb, kb_, vb, eqb, ekb, evb, ipkb, ipvb};
    int Ms_[8] = {1024, 1024, 1024, 512, 512, 512, 16, 16};
    int Ks_[8] = {3072, 3072, 3072, 3072, 3072, 3072, 2048, 2048};
    int blk = 0;
    for (int i = 0; i < 8; i++) {
      pp.j[i].A = As_[i]; pp.j[i].W = Ws_[i]; pp.j[i].bias = bs_[i]; pp.j[i].C = Cs_[i];
      pp.j[i].M = Ms_[i]; pp.j[i].K = Ks_[i]; pp.j[i].blk0 = blk; pp.j[i].out_f32 = 0;
      blk += ((Ms_[i] + 255) / 256) * 12;
    }
    pp.njobs = 8;
    k_gemm8<<<dim3(blk), 512, 131072, stream>>>(pp);  // 240 blocks
  }

  k_pack_qk<<<9312, 256, 0, stream>>>(qb, kb_, eqb, ekb, ipkb, cosr, sinr, nq, nk, naq, nak, nipq, nipk, Qf, Kff, Qip, Kip);
  k_pack_v<<<dim3(24, 49), 256, 0, stream>>>(vb, evb, ipvb, Vt, Vipt);

  // IP attention first (f32), then main attention fuses the add and writes bf16
  k_attn<<<dim3(16, 24), 256, 0, stream>>>(Qip, Kip, Vipt, (const float*)nullptr, ip_out, 1024, 64, 16, 0);
  k_attn<<<dim3(24, 24), 256, 0, stream>>>(Qf, Kff, Vt, ip_out, attnb, 1536, 1536, 1536, 1);

  // output projections: 64-row m-tiles -> 576 blocks for latency hiding
  {
    GPack pp;
    float* out = (float*)d_out;
    pp.j[0].A = attnb + (size_t)512 * 3072; pp.j[0].W = WT_[6]; pp.j[0].bias = bo;
    pp.j[0].C = out; pp.j[0].M = 1024; pp.j[0].K = 3072; pp.j[0].blk0 = 0; pp.j[0].out_f32 = 1;
    pp.j[1].A = attnb; pp.j[1].W = WT_[7]; pp.j[1].bias = bad;
    pp.j[1].C = out + (size_t)1024 * 3072; pp.j[1].M = 512; pp.j[1].K = 3072;
    pp.j[1].blk0 = (1024 / 64) * 24; pp.j[1].out_f32 = 1;
    pp.njobs = 2;
    k_gemm<64><<<dim3((1024 / 64) * 24 + (512 / 64) * 24), 256, 0, stream>>>(pp);
  }
}

// Round 3
// 676.747 us; speedup vs baseline: 1.0116x; 1.0116x over previous
//
#include <hip/hip_runtime.h>

typedef __bf16 bf16x8 __attribute__((ext_vector_type(8)));
typedef float f32x4 __attribute__((ext_vector_type(4)));
typedef unsigned short u16;
typedef unsigned int u32;

#define QSCALE 0.08838834764831845f  // 1/sqrt(128)

static __device__ __forceinline__ float bf2f(u16 u) {
  union { float f; u32 i; } x; x.i = ((u32)u) << 16; return x.f;
}
static __device__ __forceinline__ u16 f2bf(float f) {
  union { float f; u32 i; } x; x.f = f;
  u32 r = x.i + 0x7fffu + ((x.i >> 16) & 1u);
  return (u16)(r >> 16);
}
// async global->LDS, 16B per lane; lds dest must be wave-uniform base (+lane*16 by HW)
static __device__ __forceinline__ void gload16(const void* gp, void* lp) {
  __builtin_amdgcn_global_load_lds(
      (const __attribute__((address_space(1))) u32*)gp,
      (__attribute__((address_space(3))) u32*)lp, 16, 0, 0);
}

// ---------------- convert activations f32 -> bf16 ----------------
__global__ __launch_bounds__(256) void k_conv_acts(
    const float* __restrict__ hs, const float* __restrict__ ehs, const float* __restrict__ iph,
    u16* __restrict__ hsb, u16* __restrict__ ehsb, u16* __restrict__ ipb)
{
  int i = blockIdx.x * 256 + threadIdx.x;
  const float* s; u16* d; int j;
  if (i < 786432)        { s = hs;  d = hsb;  j = i; }
  else if (i < 1179648)  { s = ehs; d = ehsb; j = i - 786432; }
  else                   { s = iph; d = ipb;  j = i - 1179648; }
  float4 v = ((const float4*)s)[j];
  uint2 o;
  o.x = (u32)f2bf(v.x) | ((u32)f2bf(v.y) << 16);
  o.y = (u32)f2bf(v.z) | ((u32)f2bf(v.w) << 16);
  ((uint2*)d)[j] = o;
}

// ---------------- weight transpose+convert: src (K,3072) f32 -> dst (3072,K) bf16 ----------------
// 128x128 tile, lane carries an n-pair: float2 reads -> 512B contiguous per k-row;
// 128 k per output row -> 256B contiguous stores. LDS dword swizzle col' = c ^ (n&31):
// store-phase reads conflict-free; write-phase 4-way (measured immaterial, R1->R2).
struct WT { const float* src; u16* dst; int K; };
struct WTPack { WT w[10]; };

__global__ __launch_bounds__(256) void k_transp_w(WTPack p)
{
  WT d = p.w[blockIdx.z];
  int K = d.K;
  int k0 = blockIdx.y * 128;
  if (k0 >= K) return;
  int n0 = blockIdx.x * 128;
  __shared__ u32 T[128 * 64];   // [n][64 dw], dw c holds k-pair (2c,2c+1), swizzled
  int t = threadIdx.x;
  int lane = t & 63, w = t >> 6;       // wave w covers k-rows [32w,32w+32)
  const float* s = d.src + (size_t)(k0 + w * 32) * 3072 + n0 + lane * 2;
  float2 v[32];
  #pragma unroll
  for (int j = 0; j < 32; j++)
    v[j] = *(const float2*)(s + (size_t)j * 3072);
  int n = lane * 2;
  u32* r0 = T + (size_t)n * 64;
  u32* r1 = r0 + 64;
  int s0 = n & 31, s1 = (n + 1) & 31;
  #pragma unroll
  for (int pp = 0; pp < 16; pp++) {
    int c = w * 16 + pp;                       // dw col within 128-k tile
    float2 a = v[2 * pp], b = v[2 * pp + 1];   // k = 2c, 2c+1
    r0[c ^ s0] = (u32)f2bf(a.x) | ((u32)f2bf(b.x) << 16);
    r1[c ^ s1] = (u32)f2bf(a.y) | ((u32)f2bf(b.y) << 16);
  }
  __syncthreads();
  #pragma unroll
  for (int i = 0; i < 8; i++) {
    int idx = t + i * 256;
    int row = idx >> 4, ch = idx & 15;
    const u32* r2 = T + (size_t)row * 64;
    int sw = row & 31;
    uint4 o;
    o.x = r2[(ch * 4 + 0) ^ sw];
    o.y = r2[(ch * 4 + 1) ^ sw];
    o.z = r2[(ch * 4 + 2) ^ sw];
    o.w = r2[(ch * 4 + 3) ^ sw];
    *(uint4*)(d.dst + (size_t)(n0 + row) * K + k0 + ch * 8) = o;
  }
}

// ---------------- 8-phase 256x256 GEMM, 8 waves, counted-vmcnt pipeline ----------------
// LDS per operand: [buf2][kh2][row256][ch4 * 8bf16], chunk slot ch holds logical k-chunk ch^(row&3).
// Per K-tile (BK=64): 4 phases x 16 MFMA; each phase issues ONE half-tile (2x gload16) of prefetch.
// kh0 of tile t is read in p0/p1; p2/p3 overwrite it with tile t+2 (safe after p1 barrier).
// vmcnt(8) at p1 covers kh1(t) [read p2/p3]; vmcnt(8) at p3 covers kh0(t+1) [read next p0/p1].
struct G8Job { const u16* A; const u16* W; const float* bias; void* C; int M; int K; int blk0; int out_f32; };
struct G8Pack { G8Job j[8]; int njobs; };

__global__ __launch_bounds__(512, 2) void k_gemm8(G8Pack p)
{
  extern __shared__ __align__(16) u16 smem[];
  u16* As = smem;            // 32768 u16 = 64KB
  u16* Bs = smem + 32768;    // 64KB

  int bid = blockIdx.x;
  bid = (bid & 7) * 30 + (bid >> 3);      // XCD swizzle; grid is exactly 240 = 8*30
  int ji = 0;
  while (ji + 1 < p.njobs && bid >= p.j[ji + 1].blk0) ji++;
  G8Job J = p.j[ji];
  int local = bid - J.blk0;
  int m0 = (local / 12) * 256;
  int n0 = (local % 12) * 256;
  int K = J.K, NT = K >> 6;

  int tid = threadIdx.x, w = tid >> 6, lane = tid & 63, l15 = lane & 15, quad = lane >> 4;
  int wm = (w >> 2) * 128, wn = (w & 3) * 64;
  int dw = w * 512;                        // wave-uniform LDS slot base (u16 units)
  int cread = (quad ^ (l15 & 3)) * 8;      // frag chunk offset (u16)

  int rr = tid >> 2;                       // staging row within 128-row round
  int c4 = ((tid & 3) ^ (rr & 3)) * 8;     // pre-swizzled global chunk (u16)
  const u16* pa0 = J.A + (size_t)(m0 + rr) * K + c4;
  const u16* pa1 = pa0 + (size_t)128 * K;
  const u16* pb0 = J.W + (size_t)(n0 + rr) * K + c4;
  const u16* pb1 = pb0 + (size_t)128 * K;

  f32x4 acc[8][4] = {};
  bf16x8 af[4], bfr[4];

#define STAGE_A(b, kh, tt) do { int _ko = (tt) * 64 + (kh) * 32; int _d = ((b) * 2 + (kh)) * 8192 + dw; \
    gload16(pa0 + _ko, As + _d); gload16(pa1 + _ko, As + _d + 4096); } while (0)
#define STAGE_B(b, kh, tt) do { int _ko = (tt) * 64 + (kh) * 32; int _d = ((b) * 2 + (kh)) * 8192 + dw; \
    gload16(pb0 + _ko, Bs + _d); gload16(pb1 + _ko, Bs + _d + 4096); } while (0)

  // prologue: tile0 fully, tile1 kh0. 12 loads issued; wait leaves kh0(1) in flight.
  STAGE_A(0, 0, 0); STAGE_B(0, 0, 0); STAGE_A(0, 1, 0); STAGE_B(0, 1, 0);
  STAGE_A(1, 0, 1); STAGE_B(1, 0, 1);
  __asm__ volatile("s_waitcnt vmcnt(4)" ::: "memory");
  __builtin_amdgcn_s_barrier();

#define PHASE(ks, mtb, READB, STAGES, WAITS) do { \
    int _ab = (cur * 2 + (ks)) * 8192; \
    _Pragma("unroll") for (int i = 0; i < 4; i++) \
      af[i] = *(const bf16x8*)(As + _ab + (wm + ((mtb) + i) * 16 + l15) * 32 + cread); \
    if (READB) { _Pragma("unroll") for (int i = 0; i < 4; i++) \
      bfr[i] = *(const bf16x8*)(Bs + _ab + (wn + i * 16 + l15) * 32 + cread); } \
    STAGES; WAITS; \
    __builtin_amdgcn_s_barrier(); \
    __asm__ volatile("s_waitcnt lgkmcnt(0)" ::: "memory"); \
    __builtin_amdgcn_sched_barrier(0); \
    __builtin_amdgcn_s_setprio(1); \
    _Pragma("unroll") for (int mt = 0; mt < 4; mt++) \
      _Pragma("unroll") for (int nt = 0; nt < 4; nt++) \
        acc[(mtb) + mt][nt] = __builtin_amdgcn_mfma_f32_16x16x32_bf16(af[mt], bfr[nt], acc[(mtb) + mt][nt], 0, 0, 0); \
    __builtin_amdgcn_s_setprio(0); \
    __builtin_amdgcn_sched_barrier(0); \
    __builtin_amdgcn_s_barrier(); \
  } while (0)

  int cur = 0;
  for (int t = 0; t < NT; t++) {
    int o = cur ^ 1;
    int t1 = (t + 1 < NT) ? t + 1 : NT - 1;   // clamped prefetch (tail writes unread regions)
    int t2 = (t + 2 < NT) ? t + 2 : NT - 1;
    PHASE(0, 0, 1, STAGE_A(o, 1, t1), (void)0);
    PHASE(0, 4, 0, STAGE_B(o, 1, t1), __asm__ volatile("s_waitcnt vmcnt(8)" ::: "memory"));
    PHASE(1, 0, 1, STAGE_A(cur, 0, t2), (void)0);
    PHASE(1, 4, 0, STAGE_B(cur, 0, t2), __asm__ volatile("s_waitcnt vmcnt(8)" ::: "memory"));
    cur = o;
  }
  __asm__ volatile("s_waitcnt vmcnt(0)" ::: "memory");  // drain before LDS dealloc

  #pragma unroll
  for (int mt = 0; mt < 8; mt++) {
    int row = m0 + wm + mt * 16 + quad * 4;
    #pragma unroll
    for (int nt = 0; nt < 4; nt++) {
      int col = n0 + wn + nt * 16 + l15;
      float bv = J.bias[col];
      #pragma unroll
      for (int r = 0; r < 4; r++) {
        if (row + r < J.M) {
          float v = acc[mt][nt][r] + bv;
          if (J.out_f32) ((float*)J.C)[(size_t)(row + r) * 3072 + col] = v;
          else           ((u16*)J.C)[(size_t)(row + r) * 3072 + col] = f2bf(v);
        }
      }
    }
  }
#undef PHASE
#undef STAGE_A
#undef STAGE_B
}

// ---------------- batched GEMM (2-phase, kept for output projections) ----------------
struct GJob { const u16* A; const u16* W; const float* bias; void* C; int M; int K; int blk0; int out_f32; };
struct GPack { GJob j[8]; int njobs; };

template<int MT>
__global__ __launch_bounds__(256) void k_gemm(GPack p)
{
  __shared__ u16 As[MT * 64];
  __shared__ u16 Bs[128 * 64];
  int bid = blockIdx.x;
  int ji = 0;
  while (ji + 1 < p.njobs && bid >= p.j[ji+1].blk0) ji++;
  GJob J = p.j[ji];
  int local = bid - J.blk0;
  int m0 = (local / 24) * MT;
  int n0 = (local % 24) * 128;

  int tid = threadIdx.x, w = tid >> 6, lane = tid & 63, l15 = lane & 15, quad = lane >> 4;
  constexpr int MF = MT / 32;
  int wm = (w >> 1) * (MT / 2), wn = (w & 1) * 64;
  f32x4 acc[MF][4] = {};

  constexpr int GA = MT * 8 / 256;
  const u16* Ag[GA]; const u16* Bg[4];
  #pragma unroll
  for (int i = 0; i < GA; i++) {
    int s = i * 256 + tid;
    int row = s >> 3, kc = (s & 7) ^ (row & 7);
    Ag[i] = J.A + (size_t)(m0 + row) * J.K + kc * 8;
  }
  #pragma unroll
  for (int i = 0; i < 4; i++) {
    int s = i * 256 + tid;
    int row = s >> 3, kc = (s & 7) ^ (row & 7);
    Bg[i] = J.W + (size_t)(n0 + row) * J.K + kc * 8;
  }

  for (int k0 = 0; k0 < J.K; k0 += 64) {
    #pragma unroll
    for (int i = 0; i < GA; i++)
      gload16(Ag[i] + k0, As + (size_t)(i * 256 + w * 64) * 8);
    #pragma unroll
    for (int i = 0; i < 4; i++)
      gload16(Bg[i] + k0, Bs + (size_t)(i * 256 + w * 64) * 8);
    __syncthreads();
    int x7 = l15 & 7;
    #pragma unroll
    for (int ks = 0; ks < 2; ks++) {
      bf16x8 af[MF], bfr[4];
      #pragma unroll
      for (int t = 0; t < MF; t++)
        af[t] = *(const bf16x8*)(As + (wm + t * 16 + l15) * 64 + (((ks * 4 + quad) ^ x7) * 8));
      #pragma unroll
      for (int t = 0; t < 4; t++)
        bfr[t] = *(const bf16x8*)(Bs + (wn + t * 16 + l15) * 64 + (((ks * 4 + quad) ^ x7) * 8));
      #pragma unroll
      for (int mt = 0; mt < MF; mt++)
        #pragma unroll
        for (int nt = 0; nt < 4; nt++)
          acc[mt][nt] = __builtin_amdgcn_mfma_f32_16x16x32_bf16(af[mt], bfr[nt], acc[mt][nt], 0, 0, 0);
    }
    __syncthreads();
  }

  #pragma unroll
  for (int mt = 0; mt < MF; mt++) {
    int row = m0 + wm + mt * 16 + quad * 4;
    #pragma unroll
    for (int nt = 0; nt < 4; nt++) {
      int col = n0 + wn + nt * 16 + l15;
      float bv = J.bias[col];
      #pragma unroll
      for (int r = 0; r < 4; r++) {
        if (row + r < J.M) {
          float v = acc[mt][nt][r] + bv;
          if (J.out_f32) ((float*)J.C)[(size_t)(row + r) * 3072 + col] = v;
          else           ((u16*)J.C)[(size_t)(row + r) * 3072 + col] = f2bf(v);
        }
      }
    }
  }
}

// ---------------- pack Q/K: RMS + RoPE + scale, head-major ----------------
__global__ __launch_bounds__(256) void k_pack_qk(
    const u16* __restrict__ q, const u16* __restrict__ k,
    const u16* __restrict__ eq, const u16* __restrict__ ek,
    const u16* __restrict__ ipk,
    const float* __restrict__ cosr, const float* __restrict__ sinr,
    const float* __restrict__ nq, const float* __restrict__ nk,
    const float* __restrict__ naq, const float* __restrict__ nak,
    const float* __restrict__ nipq, const float* __restrict__ nipk,
    u16* __restrict__ Qf, u16* __restrict__ Kf, u16* __restrict__ Qip, u16* __restrict__ Kip)
{
  int u = blockIdx.x * 4 + (threadIdx.x >> 6);
  int lane = threadIdx.x & 63;
  int d0 = lane * 2;
  if (u < 36864) {
    int t = u / 24, h = u % 24;
    bool txt = t < 512;
    const u16* qrow = txt ? eq + (size_t)t * 3072 : q + (size_t)(t - 512) * 3072;
    const u16* krow = txt ? ek + (size_t)t * 3072 : k + (size_t)(t - 512) * 3072;
    u32 qv = ((const u32*)(qrow + h * 128))[lane];
    u32 kv = ((const u32*)(krow + h * 128))[lane];
    float q0 = bf2f((u16)qv), q1 = bf2f((u16)(qv >> 16));
    float k0 = bf2f((u16)kv), k1 = bf2f((u16)(kv >> 16));
    float sq = q0 * q0 + q1 * q1, sk = k0 * k0 + k1 * k1;
    #pragma unroll
    for (int off = 32; off > 0; off >>= 1) {
      sq += __shfl_xor(sq, off, 64);
      sk += __shfl_xor(sk, off, 64);
    }
    float rq = rsqrtf(sq * (1.0f / 128.0f) + 1e-6f);
    float rk = rsqrtf(sk * (1.0f / 128.0f) + 1e-6f);
    const float* wq = txt ? naq : nq;
    const float* wk = txt ? nak : nk;
    float2 c = ((const float2*)(cosr + (size_t)t * 128))[lane];
    float2 s = ((const float2*)(sinr + (size_t)t * 128))[lane];
    float xq0 = q0 * rq * wq[d0] * QSCALE, xq1 = q1 * rq * wq[d0 + 1] * QSCALE;
    float xk0 = k0 * rk * wk[d0],          xk1 = k1 * rk * wk[d0 + 1];
    u32 oq = (u32)f2bf(xq0 * c.x - xq1 * s.x) | ((u32)f2bf(xq1 * c.y + xq0 * s.y) << 16);
    u32 ok = (u32)f2bf(xk0 * c.x - xk1 * s.x) | ((u32)f2bf(xk1 * c.y + xk0 * s.y) << 16);
    ((u32*)(Qf + ((size_t)h * 1536 + t) * 128))[lane] = oq;
    ((u32*)(Kf + ((size_t)h * 1536 + t) * 128))[lane] = ok;
    if (!txt) {
      float y0 = q0 * rq * nipq[d0] * QSCALE, y1 = q1 * rq * nipq[d0 + 1] * QSCALE;
      u32 oy = (u32)f2bf(y0) | ((u32)f2bf(y1) << 16);
      ((u32*)(Qip + ((size_t)h * 1024 + (t - 512)) * 128))[lane] = oy;
    }
  } else {
    int u2 = u - 36864;
    if (u2 < 384) {
      int h = u2 >> 4, t = u2 & 15;
      u32 v = ((const u32*)(ipk + (size_t)t * 3072 + h * 128))[lane];
      float x0 = bf2f((u16)v), x1 = bf2f((u16)(v >> 16));
      float ss = x0 * x0 + x1 * x1;
      #pragma unroll
      for (int off = 32; off > 0; off >>= 1) ss += __shfl_xor(ss, off, 64);
      float rr = rsqrtf(ss * (1.0f / 128.0f) + 1e-6f);
      u32 o = (u32)f2bf(x0 * rr * nipk[d0]) | ((u32)f2bf(x1 * rr * nipk[d0 + 1]) << 16);
      ((u32*)(Kip + ((size_t)h * 64 + t) * 128))[lane] = o;   // Kip padded to 64 keys
    }
  }
}

// ---------------- pack V transposed: Vt (24,128,1536), Vipt (24,128,64) zero-padded ----------------
__global__ __launch_bounds__(256) void k_pack_v(
    const u16* __restrict__ v, const u16* __restrict__ ev, const u16* __restrict__ ipv,
    u16* __restrict__ Vt, u16* __restrict__ Vipt)
{
  __shared__ u16 T[64 * 72];
  int h = blockIdx.x, y = blockIdx.y, tid = threadIdx.x;
  if (y < 48) {
    int tb = (y % 24) * 64, db = (y / 24) * 64;
    #pragma unroll
    for (int i = 0; i < 2; i++) {
      int idx = tid + i * 256;
      int r = idx >> 3, ch = idx & 7;
      int t = tb + r;
      const u16* src = (t < 512) ? ev + (size_t)t * 3072 : v + (size_t)(t - 512) * 3072;
      uint4 val = *(const uint4*)(src + h * 128 + db + ch * 8);
      u16 tmp[8];
      *(uint4*)tmp = val;
      #pragma unroll
      for (int j = 0; j < 8; j++) T[(ch * 8 + j) * 72 + r] = tmp[j];
    }
    __syncthreads();
    #pragma unroll
    for (int i = 0; i < 2; i++) {
      int idx = tid + i * 256;
      int r = idx >> 3, ch = idx & 7;
      uint4 val = *(const uint4*)(T + r * 72 + ch * 8);
      *(uint4*)(Vt + ((size_t)h * 128 + db + r) * 1536 + tb + ch * 8) = val;
    }
  } else {
    if (tid < 128) {
      #pragma unroll
      for (int t = 0; t < 64; t++) {
        u16 val = 0;
        if (t < 16) val = ipv[(size_t)t * 3072 + h * 128 + tid];
        Vipt[((size_t)h * 128 + tid) * 64 + t] = val;  // zero pad keys 16..63
      }
    }
  }
}

// ---------------- flash attention, transposed-score formulation ----------------
__global__ __launch_bounds__(256) void k_attn(
    const u16* __restrict__ Q, const u16* __restrict__ K, const u16* __restrict__ V,
    const float* __restrict__ addend, void* __restrict__ out,
    int Sq, int Skv, int Skv_valid, int mode)
{
  __shared__ u16 Ks[64 * 128];   // [key][d-chunk swizzled]: chunk' = ch ^ (key&15)
  __shared__ u16 Vs[128 * 64];   // [d][key-chunk swizzled]: chunk' = ch ^ (d&7)
  __shared__ u16 Ps[4 * 16 * 68];
  int tid = threadIdx.x, h = blockIdx.y;
  int w = tid >> 6, lane = tid & 63, l15 = lane & 15, quad = lane >> 4;
  int mb = blockIdx.x * 64 + w * 16;

  bf16x8 aq[4];
  {
    const u16* qp = Q + ((size_t)h * Sq + mb + l15) * 128 + quad * 8;
    #pragma unroll
    for (int c = 0; c < 4; c++) aq[c] = *(const bf16x8*)(qp + c * 32);
  }

  const u16* Kg[4]; const u16* Vg[4];
  #pragma unroll
  for (int i = 0; i < 4; i++) {
    int s = tid + i * 256;
    int key = s >> 4, kc = (s & 15) ^ (key & 15);
    Kg[i] = K + ((size_t)h * Skv + key) * 128 + kc * 8;
    int d = s >> 3, vc = (s & 7) ^ (d & 7);
    Vg[i] = V + ((size_t)h * 128 + d) * Skv + vc * 8;
  }

  f32x4 o[8] = {};
  float m_col = -3.0e38f, l_col = 0.0f;
  u16* myPs = Ps + w * (16 * 68);

  for (int kb = 0; kb < Skv; kb += 64) {
    #pragma unroll
    for (int i = 0; i < 4; i++) {
      gload16(Kg[i] + (size_t)kb * 128, Ks + (i * 256 + w * 64) * 8);
      gload16(Vg[i] + kb,               Vs + (i * 256 + w * 64) * 8);
    }
    __syncthreads();

    f32x4 sc[4];
    #pragma unroll
    for (int mt = 0; mt < 4; mt++) {
      f32x4 a = {0.f, 0.f, 0.f, 0.f};
      int key = mt * 16 + l15;
      #pragma unroll
      for (int c = 0; c < 4; c++) {
        bf16x8 kf = *(const bf16x8*)(Ks + key * 128 + (((c * 4 + quad) ^ l15) * 8));
        a = __builtin_amdgcn_mfma_f32_16x16x32_bf16(kf, aq[c], a, 0, 0, 0);
      }
      sc[mt] = a;
    }
    if (Skv_valid != Skv) {
      #pragma unroll
      for (int mt = 0; mt < 4; mt++)
        #pragma unroll
        for (int r = 0; r < 4; r++)
          if (kb + mt * 16 + quad * 4 + r >= Skv_valid) sc[mt][r] = -1e30f;
    }

    float mx = sc[0][0];
    #pragma unroll
    for (int mt = 0; mt < 4; mt++)
      #pragma unroll
      for (int r = 0; r < 4; r++) mx = fmaxf(mx, sc[mt][r]);
    mx = fmaxf(mx, __shfl_xor(mx, 16, 64));
    mx = fmaxf(mx, __shfl_xor(mx, 32, 64));
    float mn = fmaxf(m_col, mx);
    float alpha = __expf(m_col - mn);
    m_col = mn;

    float sum = 0.f;
    #pragma unroll
    for (int mt = 0; mt < 4; mt++) {
      u16 pk[4];
      #pragma unroll
      for (int r = 0; r < 4; r++) {
        float pp = __expf(sc[mt][r] - mn);
        sum += pp;
        pk[r] = f2bf(pp);
      }
      uint2 pv;
      pv.x = (u32)pk[0] | ((u32)pk[1] << 16);
      pv.y = (u32)pk[2] | ((u32)pk[3] << 16);
      *(uint2*)(myPs + l15 * 68 + mt * 16 + quad * 4) = pv;
    }
    sum += __shfl_xor(sum, 16, 64);
    sum += __shfl_xor(sum, 32, 64);
    l_col = l_col * alpha + sum;

    float ar[4];
    #pragma unroll
    for (int r = 0; r < 4; r++) ar[r] = __shfl(alpha, quad * 4 + r, 64);
    #pragma unroll
    for (int nt = 0; nt < 8; nt++) {
      o[nt][0] *= ar[0]; o[nt][1] *= ar[1]; o[nt][2] *= ar[2]; o[nt][3] *= ar[3];
    }

    __asm__ volatile("s_waitcnt lgkmcnt(0)" ::: "memory");
    #pragma unroll
    for (int kc = 0; kc < 2; kc++) {
      bf16x8 pa = *(const bf16x8*)(myPs + l15 * 68 + kc * 32 + quad * 8);
      #pragma unroll
      for (int nt = 0; nt < 8; nt++) {
        int d = nt * 16 + l15;
        bf16x8 vf = *(const bf16x8*)(Vs + d * 64 + (((kc * 4 + quad) ^ (d & 7)) * 8));
        o[nt] = __builtin_amdgcn_mfma_f32_16x16x32_bf16(pa, vf, o[nt], 0, 0, 0);
      }
    }
    __syncthreads();
  }

  float linv = 1.0f / l_col;
  float lr[4];
  #pragma unroll
  for (int r = 0; r < 4; r++) lr[r] = __shfl(linv, quad * 4 + r, 64);
  #pragma unroll
  for (int r = 0; r < 4; r++) {
    int t = mb + quad * 4 + r;
    size_t base = (size_t)t * 3072 + h * 128 + l15;
    if (mode == 0) {
      float* O = (float*)out;
      #pragma unroll
      for (int nt = 0; nt < 8; nt++) O[base + nt * 16] = o[nt][r] * lr[r];
    } else {
      u16* O = (u16*)out;
      #pragma unroll
      for (int nt = 0; nt < 8; nt++) {
        float vv = o[nt][r] * lr[r];
        if (t >= 512) vv += addend[(size_t)(t - 512) * 3072 + h * 128 + nt * 16 + l15];
        O[base + nt * 16] = f2bf(vv);
      }
    }
  }
}

extern "C" void kernel_launch(void* const* d_in, const int* in_sizes, int n_in,
                              void* d_out, int out_size, void* d_ws, size_t ws_size,
                              hipStream_t stream) {
  const float* hs   = (const float*)d_in[0];
  const float* ehs  = (const float*)d_in[1];
  const float* iph  = (const float*)d_in[2];
  const float* cosr = (const float*)d_in[3];
  const float* sinr = (const float*)d_in[4];
  const float* Wq   = (const float*)d_in[5];  const float* bq   = (const float*)d_in[6];
  const float* Wk   = (const float*)d_in[7];  const float* bk   = (const float*)d_in[8];
  const float* Wv   = (const float*)d_in[9];  const float* bv   = (const float*)d_in[10];
  const float* nq   = (const float*)d_in[11]; const float* nk   = (const float*)d_in[12];
  const float* Waq  = (const float*)d_in[13]; const float* baq  = (const float*)d_in[14];
  const float* Wak  = (const float*)d_in[15]; const float* bak  = (const float*)d_in[16];
  const float* Wav  = (const float*)d_in[17]; const float* bav  = (const float*)d_in[18];
  const float* naq  = (const float*)d_in[19]; const float* nak  = (const float*)d_in[20];
  const float* Wo   = (const float*)d_in[21]; const float* bo   = (const float*)d_in[22];
  const float* Wad  = (const float*)d_in[23]; const float* bad  = (const float*)d_in[24];
  const float* Wkip = (const float*)d_in[25]; const float* bkip = (const float*)d_in[26];
  const float* Wvip = (const float*)d_in[27]; const float* bvip = (const float*)d_in[28];
  const float* nipq = (const float*)d_in[29]; const float* nipk = (const float*)d_in[30];
  (void)in_sizes; (void)n_in; (void)out_size; (void)ws_size;

  char* ws = (char*)d_ws;
  size_t off = 0;
  auto alloc = [&](size_t bytes) { size_t o = off; off += (bytes + 255) & ~(size_t)255; return o; };

  u16* hsb  = (u16*)(ws + alloc((size_t)1024 * 3072 * 2));
  u16* ehsb = (u16*)(ws + alloc((size_t)512 * 3072 * 2));
  u16* ipb  = (u16*)(ws + alloc((size_t)16 * 2048 * 2));
  u16* WT_[10];
  for (int i = 0; i < 10; i++) WT_[i] = (u16*)(ws + alloc((size_t)3072 * (i < 8 ? 3072 : 2048) * 2));
  u16* qb   = (u16*)(ws + alloc((size_t)1024 * 3072 * 2));
  u16* kb_  = (u16*)(ws + alloc((size_t)1024 * 3072 * 2));
  u16* vb   = (u16*)(ws + alloc((size_t)1024 * 3072 * 2));
  u16* eqb  = (u16*)(ws + alloc((size_t)512 * 3072 * 2));
  u16* ekb  = (u16*)(ws + alloc((size_t)512 * 3072 * 2));
  u16* evb  = (u16*)(ws + alloc((size_t)512 * 3072 * 2));
  u16* ipkb = (u16*)(ws + alloc((size_t)16 * 3072 * 2));
  u16* ipvb = (u16*)(ws + alloc((size_t)16 * 3072 * 2));
  u16* Qf   = (u16*)(ws + alloc((size_t)24 * 1536 * 128 * 2));
  u16* Kff  = (u16*)(ws + alloc((size_t)24 * 1536 * 128 * 2));
  u16* Vt   = (u16*)(ws + alloc((size_t)24 * 128 * 1536 * 2));
  u16* Qip  = (u16*)(ws + alloc((size_t)24 * 1024 * 128 * 2));
  u16* Kip  = (u16*)(ws + alloc((size_t)24 * 64 * 128 * 2));
  u16* Vipt = (u16*)(ws + alloc((size_t)24 * 128 * 64 * 2));
  float* ip_out = (float*)(ws + alloc((size_t)1024 * 3072 * 4));
  u16* attnb = (u16*)(ws + alloc((size_t)1536 * 3072 * 2));

  // allow 128KB dynamic LDS for the 8-phase GEMM (once)
  static bool attr_done = false;
  if (!attr_done) {
    hipFuncSetAttribute((const void*)k_gemm8, hipFuncAttributeMaxDynamicSharedMemorySize, 131072);
    attr_done = true;
  }

  k_conv_acts<<<4640, 256, 0, stream>>>(hs, ehs, iph, hsb, ehsb, ipb);

  WTPack p;
  const float* wsrc[10] = {Wq, Wk, Wv, Waq, Wak, Wav, Wo, Wad, Wkip, Wvip};
  for (int i = 0; i < 10; i++) { p.w[i].src = wsrc[i]; p.w[i].dst = WT_[i]; p.w[i].K = (i < 8 ? 3072 : 2048); }
  k_transp_w<<<dim3(24, 24, 10), 256, 0, stream>>>(p);

  // all 8 projection GEMMs in one 8-phase 256x256 dispatch (grid 240 = 8*30)
  {
    G8Pack pp;
    const u16* As_[8]  = {hsb, hsb, hsb, ehsb, ehsb, ehsb, ipb, ipb};
    const u16* Ws_[8]  = {WT_[0], WT_[1], WT_[2], WT_[3], WT_[4], WT_[5], WT_[8], WT_[9]};
    const float* bs_[8] = {bq, bk, bv, baq, bak, bav, bkip, bvip};
    u16* Cs_[8]        = {qb, kb_, vb, eqb, ekb, evb, ipkb, ipvb};
    int Ms_[8] = {1024, 1024, 1024, 512, 512, 512, 16, 16};
    int Ks_[8] = {3072, 3072, 3072, 3072, 3072, 3072, 2048, 2048};
    int blk = 0;
    for (int i = 0; i < 8; i++) {
      pp.j[i].A = As_[i]; pp.j[i].W = Ws_[i]; pp.j[i].bias = bs_[i]; pp.j[i].C = Cs_[i];
      pp.j[i].M = Ms_[i]; pp.j[i].K = Ks_[i]; pp.j[i].blk0 = blk; pp.j[i].out_f32 = 0;
      blk += ((Ms_[i] + 255) / 256) * 12;
    }
    pp.njobs = 8;
    k_gemm8<<<dim3(blk), 512, 131072, stream>>>(pp);  // 240 blocks
  }

  k_pack_qk<<<9312, 256, 0, stream>>>(qb, kb_, eqb, ekb, ipkb, cosr, sinr, nq, nk, naq, nak, nipq, nipk, Qf, Kff, Qip, Kip);
  k_pack_v<<<dim3(24, 49), 256, 0, stream>>>(vb, evb, ipvb, Vt, Vipt);

  // IP attention first (f32), then main attention fuses the add and writes bf16
  k_attn<<<dim3(16, 24), 256, 0, stream>>>(Qip, Kip, Vipt, (const float*)nullptr, ip_out, 1024, 64, 16, 0);
  k_attn<<<dim3(24, 24), 256, 0, stream>>>(Qf, Kff, Vt, ip_out, attnb, 1536, 1536, 1536, 1);

  // output projections: 64-row m-tiles -> 576 blocks for latency hiding
  {
    GPack pp;
    float* out = (float*)d_out;
    pp.j[0].A = attnb + (size_t)512 * 3072; pp.j[0].W = WT_[6]; pp.j[0].bias = bo;
    pp.j[0].C = out; pp.j[0].M = 1024; pp.j[0].K = 3072; pp.j[0].blk0 = 0; pp.j[0].out_f32 = 1;
    pp.j[1].A = attnb; pp.j[1].W = WT_[7]; pp.j[1].bias = bad;
    pp.j[1].C = out + (size_t)1024 * 3072; pp.j[1].M = 512; pp.j[1].K = 3072;
    pp.j[1].blk0 = (1024 / 64) * 24; pp.j[1].out_f32 = 1;
    pp.njobs = 2;
    k_gemm<64><<<dim3((1024 / 64) * 24 + (512 / 64) * 24), 256, 0, stream>>>(pp);
  }
}

// Round 4
// 662.976 us; speedup vs baseline: 1.0326x; 1.0208x over previous
//
#include <hip/hip_runtime.h>

typedef __bf16 bf16x8 __attribute__((ext_vector_type(8)));
typedef float f32x4 __attribute__((ext_vector_type(4)));
typedef unsigned short u16;
typedef unsigned int u32;

#define QSCALE 0.08838834764831845f  // 1/sqrt(128)

static __device__ __forceinline__ float bf2f(u16 u) {
  union { float f; u32 i; } x; x.i = ((u32)u) << 16; return x.f;
}
static __device__ __forceinline__ u16 f2bf(float f) {
  union { float f; u32 i; } x; x.f = f;
  u32 r = x.i + 0x7fffu + ((x.i >> 16) & 1u);
  return (u16)(r >> 16);
}
static __device__ __forceinline__ u16 bfc(float f) {
  union { __bf16 b; u16 u; } c; c.b = (__bf16)f; return c.u;   // RNE, compiler may pack
}
// async global->LDS, 16B per lane; lds dest must be wave-uniform base (+lane*16 by HW)
static __device__ __forceinline__ void gload16(const void* gp, void* lp) {
  __builtin_amdgcn_global_load_lds(
      (const __attribute__((address_space(1))) u32*)gp,
      (__attribute__((address_space(3))) u32*)lp, 16, 0, 0);
}

// ---------------- convert activations f32 -> bf16 ----------------
__global__ __launch_bounds__(256) void k_conv_acts(
    const float* __restrict__ hs, const float* __restrict__ ehs, const float* __restrict__ iph,
    u16* __restrict__ hsb, u16* __restrict__ ehsb, u16* __restrict__ ipb)
{
  int i = blockIdx.x * 256 + threadIdx.x;
  const float* s; u16* d; int j;
  if (i < 786432)        { s = hs;  d = hsb;  j = i; }
  else if (i < 1179648)  { s = ehs; d = ehsb; j = i - 786432; }
  else                   { s = iph; d = ipb;  j = i - 1179648; }
  float4 v = ((const float4*)s)[j];
  uint2 o;
  o.x = (u32)f2bf(v.x) | ((u32)f2bf(v.y) << 16);
  o.y = (u32)f2bf(v.z) | ((u32)f2bf(v.w) << 16);
  ((uint2*)d)[j] = o;
}

// ---------------- weight transpose+convert (out-proj weights only now) ----------------
struct WT { const float* src; u16* dst; int K; };
struct WTPack { WT w[2]; };

__global__ __launch_bounds__(256) void k_transp_w(WTPack p)
{
  WT d = p.w[blockIdx.z];
  int K = d.K;
  int k0 = blockIdx.y * 128;
  if (k0 >= K) return;
  int n0 = blockIdx.x * 128;
  __shared__ u32 T[128 * 64];   // [n][64 dw], dw c holds k-pair (2c,2c+1), swizzled
  int t = threadIdx.x;
  int lane = t & 63, w = t >> 6;       // wave w covers k-rows [32w,32w+32)
  const float* s = d.src + (size_t)(k0 + w * 32) * 3072 + n0 + lane * 2;
  float2 v[32];
  #pragma unroll
  for (int j = 0; j < 32; j++)
    v[j] = *(const float2*)(s + (size_t)j * 3072);
  int n = lane * 2;
  u32* r0 = T + (size_t)n * 64;
  u32* r1 = r0 + 64;
  int s0 = n & 31, s1 = (n + 1) & 31;
  #pragma unroll
  for (int pp = 0; pp < 16; pp++) {
    int c = w * 16 + pp;                       // dw col within 128-k tile
    float2 a = v[2 * pp], b = v[2 * pp + 1];   // k = 2c, 2c+1
    r0[c ^ s0] = (u32)f2bf(a.x) | ((u32)f2bf(b.x) << 16);
    r1[c ^ s1] = (u32)f2bf(a.y) | ((u32)f2bf(b.y) << 16);
  }
  __syncthreads();
  #pragma unroll
  for (int i = 0; i < 8; i++) {
    int idx = t + i * 256;
    int row = idx >> 4, ch = idx & 15;
    const u32* r2 = T + (size_t)row * 64;
    int sw = row & 31;
    uint4 o;
    o.x = r2[(ch * 4 + 0) ^ sw];
    o.y = r2[(ch * 4 + 1) ^ sw];
    o.z = r2[(ch * 4 + 2) ^ sw];
    o.w = r2[(ch * 4 + 3) ^ sw];
    *(uint4*)(d.dst + (size_t)(n0 + row) * K + k0 + ch * 8) = o;
  }
}

// ---------------- 8-phase 256x256 GEMM, 8 waves, native-f32 B staging ----------------
// A (bf16, K-contig) staged via global_load_lds; B (f32, (K,3072) native) staged via
// reg-load float2 -> cvt bf16 -> ds_write_b128 into the swizzled [n][k] LDS layout
// (fuses the old weight transpose into the GEMM; removes 336 MiB of pre-pass traffic).
// Issue schedule per tile t (cur=t&1, o=cur^1):
//   P0: frags ks0; issue Aa(t+1,kh1 -> buf o) [2 gload_lds]
//   P1: frags ks0 (m4-7)
//   P2: vmcnt(20) [Aa(t) landed]; frags ks1; B_WRITE(t+1 -> buf o) [regs auto-waited];
//       B_ISSUE(t+2) [16 float2]; Ab(t+2,kh0 -> buf cur) [2 gload_lds]
//   P3: frags ks1 (m4-7); vmcnt(18) [everything except the 18 P2-issued ops -> Ab(t+1) landed]
// Waits are order-robust: vmcnt(20)=oldest-2 drained, vmcnt(18)=exactly the P2-issued set left.
struct G8Job { const u16* A; const float* Wf; const float* bias; void* C; int M; int K; int blk0; int out_f32; };
struct G8Pack { G8Job j[8]; int njobs; };

__global__ __launch_bounds__(512, 2) void k_gemm8(G8Pack p)
{
  extern __shared__ __align__(16) u16 smem[];
  u16* As = smem;            // 32768 u16 = 64KB
  u16* Bs = smem + 32768;    // 64KB

  int bid = blockIdx.x;
  bid = (bid & 7) * 30 + (bid >> 3);      // XCD swizzle; grid is exactly 240 = 8*30
  int ji = 0;
  while (ji + 1 < p.njobs && bid >= p.j[ji + 1].blk0) ji++;
  G8Job J = p.j[ji];
  int local = bid - J.blk0;
  int m0 = (local / 12) * 256;
  int n0 = (local % 12) * 256;
  int K = J.K, NT = K >> 6;

  int tid = threadIdx.x, w = tid >> 6, lane = tid & 63, l15 = lane & 15, quad = lane >> 4;
  int wm = (w >> 2) * 128, wn = (w & 3) * 64;
  int dw = w * 512;                        // wave-uniform LDS slot base (u16 units)
  int cread = (quad ^ (l15 & 3)) * 8;      // frag chunk offset (u16)

  // A staging (global_load_lds, pre-swizzled source chunk)
  int rr = tid >> 2;
  int c4 = ((tid & 3) ^ (rr & 3)) * 8;
  const u16* pa0 = J.A + (size_t)(m0 + rr) * K + c4;
  const u16* pa1 = pa0 + (size_t)128 * K;

  // B staging (reg): thread covers cols nB,nB+1 x k-rows [kcB*16, kcB*16+16) of each K-tile
  int nB = (tid & 127) * 2;
  int kcB = tid >> 7;                  // 0..3
  int khB = kcB >> 1;                  // half
  const float* pw = J.Wf + (size_t)(kcB * 16) * 3072 + n0 + nB;

  float2 ld[16];
  f32x4 acc[8][4] = {};
  bf16x8 af[4], bfr[4];

#define A_GLOAD(b, kh, tt) do { size_t _ko = (size_t)(tt) * 64 + (kh) * 32; int _d = ((b) * 2 + (kh)) * 8192 + dw; \
    gload16(pa0 + _ko, As + _d); gload16(pa1 + _ko, As + _d + 4096); } while (0)
#define B_ISSUE(tt) do { const float* _s = pw + (size_t)(tt) * 64 * 3072; \
    _Pragma("unroll") for (int j = 0; j < 16; j++) ld[j] = *(const float2*)(_s + (size_t)j * 3072); } while (0)
#define B_WRITE(b) do { \
    _Pragma("unroll") for (int j2 = 0; j2 < 2; j2++) { \
      int _c = 2 * (kcB & 1) + j2; \
      u16 t0[8], t1[8]; \
      _Pragma("unroll") for (int i = 0; i < 8; i++) { float2 _v = ld[j2 * 8 + i]; t0[i] = bfc(_v.x); t1[i] = bfc(_v.y); } \
      *(uint4*)(Bs + ((b) * 2 + khB) * 8192 + nB * 32 + ((_c ^ (nB & 3))) * 8) = *(uint4*)t0; \
      *(uint4*)(Bs + ((b) * 2 + khB) * 8192 + (nB + 1) * 32 + ((_c ^ ((nB + 1) & 3))) * 8) = *(uint4*)t1; \
    } } while (0)
#define FRAGS_A(mtb, ks) do { int _ab = (cur * 2 + (ks)) * 8192; \
    _Pragma("unroll") for (int i = 0; i < 4; i++) \
      af[i] = *(const bf16x8*)(As + _ab + (wm + ((mtb) + i) * 16 + l15) * 32 + cread); } while (0)
#define FRAGS_B(ks) do { int _ab = (cur * 2 + (ks)) * 8192; \
    _Pragma("unroll") for (int i = 0; i < 4; i++) \
      bfr[i] = *(const bf16x8*)(Bs + _ab + (wn + i * 16 + l15) * 32 + cread); } while (0)
#define MFMA16(mtb) do { \
    __builtin_amdgcn_s_barrier(); \
    __asm__ volatile("s_waitcnt lgkmcnt(0)" ::: "memory"); \
    __builtin_amdgcn_sched_barrier(0); \
    __builtin_amdgcn_s_setprio(1); \
    _Pragma("unroll") for (int mt = 0; mt < 4; mt++) \
      _Pragma("unroll") for (int nt = 0; nt < 4; nt++) \
        acc[(mtb) + mt][nt] = __builtin_amdgcn_mfma_f32_16x16x32_bf16(af[mt], bfr[nt], acc[(mtb) + mt][nt], 0, 0, 0); \
    __builtin_amdgcn_s_setprio(0); \
    __builtin_amdgcn_sched_barrier(0); \
    __builtin_amdgcn_s_barrier(); \
  } while (0)

  // prologue: B0 regs; A0 (both halves); write B0; B1 regs; Ab(1).
  B_ISSUE(0);
  A_GLOAD(0, 0, 0);
  A_GLOAD(0, 1, 0);
  B_WRITE(0);                      // compiler auto-waits B0 regs
  B_ISSUE(1);
  A_GLOAD(1, 0, 1);
  __asm__ volatile("s_waitcnt vmcnt(18)" ::: "memory");   // A0 both halves landed
  __asm__ volatile("s_waitcnt lgkmcnt(0)" ::: "memory");  // B0 ds_writes done
  __builtin_amdgcn_s_barrier();

  int cur = 0;
  for (int t = 0; t < NT; t++) {
    int o = cur ^ 1;
    int t1c = (t + 1 < NT) ? t + 1 : NT - 1;
    int t2c = (t + 2 < NT) ? t + 2 : NT - 1;
    // P0
    FRAGS_A(0, 0); FRAGS_B(0);
    A_GLOAD(o, 1, t1c);            // Aa(t+1) -> buf o kh1
    MFMA16(0);
    // P1
    FRAGS_A(4, 0);
    MFMA16(4);
    // P2
    __asm__ volatile("s_waitcnt vmcnt(20)" ::: "memory");  // Aa(t) kh1 landed
    FRAGS_A(0, 1); FRAGS_B(1);
    B_WRITE(o);                    // B(t+1) -> buf o (regs auto-waited)
    B_ISSUE(t2c);                  // B(t+2) regs
    A_GLOAD(cur, 0, t2c);          // Ab(t+2) -> buf cur kh0
    MFMA16(0);
    // P3
    FRAGS_A(4, 1);
    __asm__ volatile("s_waitcnt vmcnt(18)" ::: "memory");  // all but P2-issued set -> Ab(t+1) landed
    MFMA16(4);
    cur = o;
  }
  __asm__ volatile("s_waitcnt vmcnt(0)" ::: "memory");  // drain before LDS dealloc

  #pragma unroll
  for (int mt = 0; mt < 8; mt++) {
    int row = m0 + wm + mt * 16 + quad * 4;
    #pragma unroll
    for (int nt = 0; nt < 4; nt++) {
      int col = n0 + wn + nt * 16 + l15;
      float bv = J.bias[col];
      #pragma unroll
      for (int r = 0; r < 4; r++) {
        if (row + r < J.M) {
          float v = acc[mt][nt][r] + bv;
          if (J.out_f32) ((float*)J.C)[(size_t)(row + r) * 3072 + col] = v;
          else           ((u16*)J.C)[(size_t)(row + r) * 3072 + col] = f2bf(v);
        }
      }
    }
  }
#undef MFMA16
#undef FRAGS_B
#undef FRAGS_A
#undef B_WRITE
#undef B_ISSUE
#undef A_GLOAD
}

// ---------------- batched GEMM (2-phase, kept for output projections) ----------------
struct GJob { const u16* A; const u16* W; const float* bias; void* C; int M; int K; int blk0; int out_f32; };
struct GPack { GJob j[8]; int njobs; };

template<int MT>
__global__ __launch_bounds__(256) void k_gemm(GPack p)
{
  __shared__ u16 As[MT * 64];
  __shared__ u16 Bs[128 * 64];
  int bid = blockIdx.x;
  int ji = 0;
  while (ji + 1 < p.njobs && bid >= p.j[ji+1].blk0) ji++;
  GJob J = p.j[ji];
  int local = bid - J.blk0;
  int m0 = (local / 24) * MT;
  int n0 = (local % 24) * 128;

  int tid = threadIdx.x, w = tid >> 6, lane = tid & 63, l15 = lane & 15, quad = lane >> 4;
  constexpr int MF = MT / 32;
  int wm = (w >> 1) * (MT / 2), wn = (w & 1) * 64;
  f32x4 acc[MF][4] = {};

  constexpr int GA = MT * 8 / 256;
  const u16* Ag[GA]; const u16* Bg[4];
  #pragma unroll
  for (int i = 0; i < GA; i++) {
    int s = i * 256 + tid;
    int row = s >> 3, kc = (s & 7) ^ (row & 7);
    Ag[i] = J.A + (size_t)(m0 + row) * J.K + kc * 8;
  }
  #pragma unroll
  for (int i = 0; i < 4; i++) {
    int s = i * 256 + tid;
    int row = s >> 3, kc = (s & 7) ^ (row & 7);
    Bg[i] = J.W + (size_t)(n0 + row) * J.K + kc * 8;
  }

  for (int k0 = 0; k0 < J.K; k0 += 64) {
    #pragma unroll
    for (int i = 0; i < GA; i++)
      gload16(Ag[i] + k0, As + (size_t)(i * 256 + w * 64) * 8);
    #pragma unroll
    for (int i = 0; i < 4; i++)
      gload16(Bg[i] + k0, Bs + (size_t)(i * 256 + w * 64) * 8);
    __syncthreads();
    int x7 = l15 & 7;
    #pragma unroll
    for (int ks = 0; ks < 2; ks++) {
      bf16x8 af[MF], bfr[4];
      #pragma unroll
      for (int t = 0; t < MF; t++)
        af[t] = *(const bf16x8*)(As + (wm + t * 16 + l15) * 64 + (((ks * 4 + quad) ^ x7) * 8));
      #pragma unroll
      for (int t = 0; t < 4; t++)
        bfr[t] = *(const bf16x8*)(Bs + (wn + t * 16 + l15) * 64 + (((ks * 4 + quad) ^ x7) * 8));
      #pragma unroll
      for (int mt = 0; mt < MF; mt++)
        #pragma unroll
        for (int nt = 0; nt < 4; nt++)
          acc[mt][nt] = __builtin_amdgcn_mfma_f32_16x16x32_bf16(af[mt], bfr[nt], acc[mt][nt], 0, 0, 0);
    }
    __syncthreads();
  }

  #pragma unroll
  for (int mt = 0; mt < MF; mt++) {
    int row = m0 + wm + mt * 16 + quad * 4;
    #pragma unroll
    for (int nt = 0; nt < 4; nt++) {
      int col = n0 + wn + nt * 16 + l15;
      float bv = J.bias[col];
      #pragma unroll
      for (int r = 0; r < 4; r++) {
        if (row + r < J.M) {
          float v = acc[mt][nt][r] + bv;
          if (J.out_f32) ((float*)J.C)[(size_t)(row + r) * 3072 + col] = v;
          else           ((u16*)J.C)[(size_t)(row + r) * 3072 + col] = f2bf(v);
        }
      }
    }
  }
}

// ---------------- pack Q/K: RMS + RoPE + scale, head-major ----------------
__global__ __launch_bounds__(256) void k_pack_qk(
    const u16* __restrict__ q, const u16* __restrict__ k,
    const u16* __restrict__ eq, const u16* __restrict__ ek,
    const u16* __restrict__ ipk,
    const float* __restrict__ cosr, const float* __restrict__ sinr,
    const float* __restrict__ nq, const float* __restrict__ nk,
    const float* __restrict__ naq, const float* __restrict__ nak,
    const float* __restrict__ nipq, const float* __restrict__ nipk,
    u16* __restrict__ Qf, u16* __restrict__ Kf, u16* __restrict__ Qip, u16* __restrict__ Kip)
{
  int u = blockIdx.x * 4 + (threadIdx.x >> 6);
  int lane = threadIdx.x & 63;
  int d0 = lane * 2;
  if (u < 36864) {
    int t = u / 24, h = u % 24;
    bool txt = t < 512;
    const u16* qrow = txt ? eq + (size_t)t * 3072 : q + (size_t)(t - 512) * 3072;
    const u16* krow = txt ? ek + (size_t)t * 3072 : k + (size_t)(t - 512) * 3072;
    u32 qv = ((const u32*)(qrow + h * 128))[lane];
    u32 kv = ((const u32*)(krow + h * 128))[lane];
    float q0 = bf2f((u16)qv), q1 = bf2f((u16)(qv >> 16));
    float k0 = bf2f((u16)kv), k1 = bf2f((u16)(kv >> 16));
    float sq = q0 * q0 + q1 * q1, sk = k0 * k0 + k1 * k1;
    #pragma unroll
    for (int off = 32; off > 0; off >>= 1) {
      sq += __shfl_xor(sq, off, 64);
      sk += __shfl_xor(sk, off, 64);
    }
    float rq = rsqrtf(sq * (1.0f / 128.0f) + 1e-6f);
    float rk = rsqrtf(sk * (1.0f / 128.0f) + 1e-6f);
    const float* wq = txt ? naq : nq;
    const float* wk = txt ? nak : nk;
    float2 c = ((const float2*)(cosr + (size_t)t * 128))[lane];
    float2 s = ((const float2*)(sinr + (size_t)t * 128))[lane];
    float xq0 = q0 * rq * wq[d0] * QSCALE, xq1 = q1 * rq * wq[d0 + 1] * QSCALE;
    float xk0 = k0 * rk * wk[d0],          xk1 = k1 * rk * wk[d0 + 1];
    u32 oq = (u32)f2bf(xq0 * c.x - xq1 * s.x) | ((u32)f2bf(xq1 * c.y + xq0 * s.y) << 16);
    u32 ok = (u32)f2bf(xk0 * c.x - xk1 * s.x) | ((u32)f2bf(xk1 * c.y + xk0 * s.y) << 16);
    ((u32*)(Qf + ((size_t)h * 1536 + t) * 128))[lane] = oq;
    ((u32*)(Kf + ((size_t)h * 1536 + t) * 128))[lane] = ok;
    if (!txt) {
      float y0 = q0 * rq * nipq[d0] * QSCALE, y1 = q1 * rq * nipq[d0 + 1] * QSCALE;
      u32 oy = (u32)f2bf(y0) | ((u32)f2bf(y1) << 16);
      ((u32*)(Qip + ((size_t)h * 1024 + (t - 512)) * 128))[lane] = oy;
    }
  } else {
    int u2 = u - 36864;
    if (u2 < 384) {
      int h = u2 >> 4, t = u2 & 15;
      u32 v = ((const u32*)(ipk + (size_t)t * 3072 + h * 128))[lane];
      float x0 = bf2f((u16)v), x1 = bf2f((u16)(v >> 16));
      float ss = x0 * x0 + x1 * x1;
      #pragma unroll
      for (int off = 32; off > 0; off >>= 1) ss += __shfl_xor(ss, off, 64);
      float rr = rsqrtf(ss * (1.0f / 128.0f) + 1e-6f);
      u32 o = (u32)f2bf(x0 * rr * nipk[d0]) | ((u32)f2bf(x1 * rr * nipk[d0 + 1]) << 16);
      ((u32*)(Kip + ((size_t)h * 64 + t) * 128))[lane] = o;   // Kip padded to 64 keys
    }
  }
}

// ---------------- pack V transposed: Vt (24,128,1536), Vipt (24,128,64) zero-padded ----------------
__global__ __launch_bounds__(256) void k_pack_v(
    const u16* __restrict__ v, const u16* __restrict__ ev, const u16* __restrict__ ipv,
    u16* __restrict__ Vt, u16* __restrict__ Vipt)
{
  __shared__ u16 T[64 * 72];
  int h = blockIdx.x, y = blockIdx.y, tid = threadIdx.x;
  if (y < 48) {
    int tb = (y % 24) * 64, db = (y / 24) * 64;
    #pragma unroll
    for (int i = 0; i < 2; i++) {
      int idx = tid + i * 256;
      int r = idx >> 3, ch = idx & 7;
      int t = tb + r;
      const u16* src = (t < 512) ? ev + (size_t)t * 3072 : v + (size_t)(t - 512) * 3072;
      uint4 val = *(const uint4*)(src + h * 128 + db + ch * 8);
      u16 tmp[8];
      *(uint4*)tmp = val;
      #pragma unroll
      for (int j = 0; j < 8; j++) T[(ch * 8 + j) * 72 + r] = tmp[j];
    }
    __syncthreads();
    #pragma unroll
    for (int i = 0; i < 2; i++) {
      int idx = tid + i * 256;
      int r = idx >> 3, ch = idx & 7;
      uint4 val = *(const uint4*)(T + r * 72 + ch * 8);
      *(uint4*)(Vt + ((size_t)h * 128 + db + r) * 1536 + tb + ch * 8) = val;
    }
  } else {
    if (tid < 128) {
      #pragma unroll
      for (int t = 0; t < 64; t++) {
        u16 val = 0;
        if (t < 16) val = ipv[(size_t)t * 3072 + h * 128 + tid];
        Vipt[((size_t)h * 128 + tid) * 64 + t] = val;  // zero pad keys 16..63
      }
    }
  }
}

// ---------------- flash attention, transposed-score formulation ----------------
__global__ __launch_bounds__(256) void k_attn(
    const u16* __restrict__ Q, const u16* __restrict__ K, const u16* __restrict__ V,
    const float* __restrict__ addend, void* __restrict__ out,
    int Sq, int Skv, int Skv_valid, int mode)
{
  __shared__ u16 Ks[64 * 128];   // [key][d-chunk swizzled]: chunk' = ch ^ (key&15)
  __shared__ u16 Vs[128 * 64];   // [d][key-chunk swizzled]: chunk' = ch ^ (d&7)
  __shared__ u16 Ps[4 * 16 * 68];
  int tid = threadIdx.x, h = blockIdx.y;
  int w = tid >> 6, lane = tid & 63, l15 = lane & 15, quad = lane >> 4;
  int mb = blockIdx.x * 64 + w * 16;

  bf16x8 aq[4];
  {
    const u16* qp = Q + ((size_t)h * Sq + mb + l15) * 128 + quad * 8;
    #pragma unroll
    for (int c = 0; c < 4; c++) aq[c] = *(const bf16x8*)(qp + c * 32);
  }

  const u16* Kg[4]; const u16* Vg[4];
  #pragma unroll
  for (int i = 0; i < 4; i++) {
    int s = tid + i * 256;
    int key = s >> 4, kc = (s & 15) ^ (key & 15);
    Kg[i] = K + ((size_t)h * Skv + key) * 128 + kc * 8;
    int d = s >> 3, vc = (s & 7) ^ (d & 7);
    Vg[i] = V + ((size_t)h * 128 + d) * Skv + vc * 8;
  }

  f32x4 o[8] = {};
  float m_col = -3.0e38f, l_col = 0.0f;
  u16* myPs = Ps + w * (16 * 68);

  for (int kb = 0; kb < Skv; kb += 64) {
    #pragma unroll
    for (int i = 0; i < 4; i++) {
      gload16(Kg[i] + (size_t)kb * 128, Ks + (i * 256 + w * 64) * 8);
      gload16(Vg[i] + kb,               Vs + (i * 256 + w * 64) * 8);
    }
    __syncthreads();

    f32x4 sc[4];
    #pragma unroll
    for (int mt = 0; mt < 4; mt++) {
      f32x4 a = {0.f, 0.f, 0.f, 0.f};
      int key = mt * 16 + l15;
      #pragma unroll
      for (int c = 0; c < 4; c++) {
        bf16x8 kf = *(const bf16x8*)(Ks + key * 128 + (((c * 4 + quad) ^ l15) * 8));
        a = __builtin_amdgcn_mfma_f32_16x16x32_bf16(kf, aq[c], a, 0, 0, 0);
      }
      sc[mt] = a;
    }
    if (Skv_valid != Skv) {
      #pragma unroll
      for (int mt = 0; mt < 4; mt++)
        #pragma unroll
        for (int r = 0; r < 4; r++)
          if (kb + mt * 16 + quad * 4 + r >= Skv_valid) sc[mt][r] = -1e30f;
    }

    float mx = sc[0][0];
    #pragma unroll
    for (int mt = 0; mt < 4; mt++)
      #pragma unroll
      for (int r = 0; r < 4; r++) mx = fmaxf(mx, sc[mt][r]);
    mx = fmaxf(mx, __shfl_xor(mx, 16, 64));
    mx = fmaxf(mx, __shfl_xor(mx, 32, 64));
    float mn = fmaxf(m_col, mx);
    float alpha = __expf(m_col - mn);
    m_col = mn;

    float sum = 0.f;
    #pragma unroll
    for (int mt = 0; mt < 4; mt++) {
      u16 pk[4];
      #pragma unroll
      for (int r = 0; r < 4; r++) {
        float pp = __expf(sc[mt][r] - mn);
        sum += pp;
        pk[r] = f2bf(pp);
      }
      uint2 pv;
      pv.x = (u32)pk[0] | ((u32)pk[1] << 16);
      pv.y = (u32)pk[2] | ((u32)pk[3] << 16);
      *(uint2*)(myPs + l15 * 68 + mt * 16 + quad * 4) = pv;
    }
    sum += __shfl_xor(sum, 16, 64);
    sum += __shfl_xor(sum, 32, 64);
    l_col = l_col * alpha + sum;

    float ar[4];
    #pragma unroll
    for (int r = 0; r < 4; r++) ar[r] = __shfl(alpha, quad * 4 + r, 64);
    #pragma unroll
    for (int nt = 0; nt < 8; nt++) {
      o[nt][0] *= ar[0]; o[nt][1] *= ar[1]; o[nt][2] *= ar[2]; o[nt][3] *= ar[3];
    }

    __asm__ volatile("s_waitcnt lgkmcnt(0)" ::: "memory");
    #pragma unroll
    for (int kc = 0; kc < 2; kc++) {
      bf16x8 pa = *(const bf16x8*)(myPs + l15 * 68 + kc * 32 + quad * 8);
      #pragma unroll
      for (int nt = 0; nt < 8; nt++) {
        int d = nt * 16 + l15;
        bf16x8 vf = *(const bf16x8*)(Vs + d * 64 + (((kc * 4 + quad) ^ (d & 7)) * 8));
        o[nt] = __builtin_amdgcn_mfma_f32_16x16x32_bf16(pa, vf, o[nt], 0, 0, 0);
      }
    }
    __syncthreads();
  }

  float linv = 1.0f / l_col;
  float lr[4];
  #pragma unroll
  for (int r = 0; r < 4; r++) lr[r] = __shfl(linv, quad * 4 + r, 64);
  #pragma unroll
  for (int r = 0; r < 4; r++) {
    int t = mb + quad * 4 + r;
    size_t base = (size_t)t * 3072 + h * 128 + l15;
    if (mode == 0) {
      float* O = (float*)out;
      #pragma unroll
      for (int nt = 0; nt < 8; nt++) O[base + nt * 16] = o[nt][r] * lr[r];
    } else {
      u16* O = (u16*)out;
      #pragma unroll
      for (int nt = 0; nt < 8; nt++) {
        float vv = o[nt][r] * lr[r];
        if (t >= 512) vv += addend[(size_t)(t - 512) * 3072 + h * 128 + nt * 16 + l15];
        O[base + nt * 16] = f2bf(vv);
      }
    }
  }
}

extern "C" void kernel_launch(void* const* d_in, const int* in_sizes, int n_in,
                              void* d_out, int out_size, void* d_ws, size_t ws_size,
                              hipStream_t stream) {
  const float* hs   = (const float*)d_in[0];
  const float* ehs  = (const float*)d_in[1];
  const float* iph  = (const float*)d_in[2];
  const float* cosr = (const float*)d_in[3];
  const float* sinr = (const float*)d_in[4];
  const float* Wq   = (const float*)d_in[5];  const float* bq   = (const float*)d_in[6];
  const float* Wk   = (const float*)d_in[7];  const float* bk   = (const float*)d_in[8];
  const float* Wv   = (const float*)d_in[9];  const float* bv   = (const float*)d_in[10];
  const float* nq   = (const float*)d_in[11]; const float* nk   = (const float*)d_in[12];
  const float* Waq  = (const float*)d_in[13]; const float* baq  = (const float*)d_in[14];
  const float* Wak  = (const float*)d_in[15]; const float* bak  = (const float*)d_in[16];
  const float* Wav  = (const float*)d_in[17]; const float* bav  = (const float*)d_in[18];
  const float* naq  = (const float*)d_in[19]; const float* nak  = (const float*)d_in[20];
  const float* Wo   = (const float*)d_in[21]; const float* bo   = (const float*)d_in[22];
  const float* Wad  = (const float*)d_in[23]; const float* bad  = (const float*)d_in[24];
  const float* Wkip = (const float*)d_in[25]; const float* bkip = (const float*)d_in[26];
  const float* Wvip = (const float*)d_in[27]; const float* bvip = (const float*)d_in[28];
  const float* nipq = (const float*)d_in[29]; const float* nipk = (const float*)d_in[30];
  (void)in_sizes; (void)n_in; (void)out_size; (void)ws_size;

  char* ws = (char*)d_ws;
  size_t off = 0;
  auto alloc = [&](size_t bytes) { size_t o = off; off += (bytes + 255) & ~(size_t)255; return o; };

  u16* hsb  = (u16*)(ws + alloc((size_t)1024 * 3072 * 2));
  u16* ehsb = (u16*)(ws + alloc((size_t)512 * 3072 * 2));
  u16* ipb  = (u16*)(ws + alloc((size_t)16 * 2048 * 2));
  u16* WT_[2];
  for (int i = 0; i < 2; i++) WT_[i] = (u16*)(ws + alloc((size_t)3072 * 3072 * 2));
  u16* qb   = (u16*)(ws + alloc((size_t)1024 * 3072 * 2));
  u16* kb_  = (u16*)(ws + alloc((size_t)1024 * 3072 * 2));
  u16* vb   = (u16*)(ws + alloc((size_t)1024 * 3072 * 2));
  u16* eqb  = (u16*)(ws + alloc((size_t)512 * 3072 * 2));
  u16* ekb  = (u16*)(ws + alloc((size_t)512 * 3072 * 2));
  u16* evb  = (u16*)(ws + alloc((size_t)512 * 3072 * 2));
  u16* ipkb = (u16*)(ws + alloc((size_t)16 * 3072 * 2));
  u16* ipvb = (u16*)(ws + alloc((size_t)16 * 3072 * 2));
  u16* Qf   = (u16*)(ws + alloc((size_t)24 * 1536 * 128 * 2));
  u16* Kff  = (u16*)(ws + alloc((size_t)24 * 1536 * 128 * 2));
  u16* Vt   = (u16*)(ws + alloc((size_t)24 * 128 * 1536 * 2));
  u16* Qip  = (u16*)(ws + alloc((size_t)24 * 1024 * 128 * 2));
  u16* Kip  = (u16*)(ws + alloc((size_t)24 * 64 * 128 * 2));
  u16* Vipt = (u16*)(ws + alloc((size_t)24 * 128 * 64 * 2));
  float* ip_out = (float*)(ws + alloc((size_t)1024 * 3072 * 4));
  u16* attnb = (u16*)(ws + alloc((size_t)1536 * 3072 * 2));

  // allow 128KB dynamic LDS for the 8-phase GEMM (once)
  static bool attr_done = false;
  if (!attr_done) {
    hipFuncSetAttribute((const void*)k_gemm8, hipFuncAttributeMaxDynamicSharedMemorySize, 131072);
    attr_done = true;
  }

  k_conv_acts<<<4640, 256, 0, stream>>>(hs, ehs, iph, hsb, ehsb, ipb);

  // transpose only the out-projection weights (Wo, Wad)
  WTPack p;
  p.w[0].src = Wo;  p.w[0].dst = WT_[0]; p.w[0].K = 3072;
  p.w[1].src = Wad; p.w[1].dst = WT_[1]; p.w[1].K = 3072;
  k_transp_w<<<dim3(24, 24, 2), 256, 0, stream>>>(p);

  // all 8 projection GEMMs in one 8-phase 256x256 dispatch, native f32 weights (grid 240 = 8*30)
  {
    G8Pack pp;
    const u16* As_[8]    = {hsb, hsb, hsb, ehsb, ehsb, ehsb, ipb, ipb};
    const float* Ws_[8]  = {Wq, Wk, Wv, Waq, Wak, Wav, Wkip, Wvip};
    const float* bs_[8]  = {bq, bk, bv, baq, bak, bav, bkip, bvip};
    u16* Cs_[8]          = {qb, kb_, vb, eqb, ekb, evb, ipkb, ipvb};
    int Ms_[8] = {1024, 1024, 1024, 512, 512, 512, 16, 16};
    int Ks_[8] = {3072, 3072, 3072, 3072, 3072, 3072, 2048, 2048};
    int blk = 0;
    for (int i = 0; i < 8; i++) {
      pp.j[i].A = As_[i]; pp.j[i].Wf = Ws_[i]; pp.j[i].bias = bs_[i]; pp.j[i].C = Cs_[i];
      pp.j[i].M = Ms_[i]; pp.j[i].K = Ks_[i]; pp.j[i].blk0 = blk; pp.j[i].out_f32 = 0;
      blk += ((Ms_[i] + 255) / 256) * 12;
    }
    pp.njobs = 8;
    k_gemm8<<<dim3(blk), 512, 131072, stream>>>(pp);  // 240 blocks
  }

  k_pack_qk<<<9312, 256, 0, stream>>>(qb, kb_, eqb, ekb, ipkb, cosr, sinr, nq, nk, naq, nak, nipq, nipk, Qf, Kff, Qip, Kip);
  k_pack_v<<<dim3(24, 49), 256, 0, stream>>>(vb, evb, ipvb, Vt, Vipt);

  // IP attention first (f32), then main attention fuses the add and writes bf16
  k_attn<<<dim3(16, 24), 256, 0, stream>>>(Qip, Kip, Vipt, (const float*)nullptr, ip_out, 1024, 64, 16, 0);
  k_attn<<<dim3(24, 24), 256, 0, stream>>>(Qf, Kff, Vt, ip_out, attnb, 1536, 1536, 1536, 1);

  // output projections: 64-row m-tiles -> 576 blocks for latency hiding
  {
    GPack pp;
    float* out = (float*)d_out;
    pp.j[0].A = attnb + (size_t)512 * 3072; pp.j[0].W = WT_[0]; pp.j[0].bias = bo;
    pp.j[0].C = out; pp.j[0].M = 1024; pp.j[0].K = 3072; pp.j[0].blk0 = 0; pp.j[0].out_f32 = 1;
    pp.j[1].A = attnb; pp.j[1].W = WT_[1]; pp.j[1].bias = bad;
    pp.j[1].C = out + (size_t)1024 * 3072; pp.j[1].M = 512; pp.j[1].K = 3072;
    pp.j[1].blk0 = (1024 / 64) * 24; pp.j[1].out_f32 = 1;
    pp.njobs = 2;
    k_gemm<64><<<dim3((1024 / 64) * 24 + (512 / 64) * 24), 256, 0, stream>>>(pp);
  }
}